// Round 9
// baseline (408.370 us; speedup 1.0000x reference)
//
#include <hip/hip_runtime.h>

#define NEG_SLOPE 0.2f

typedef unsigned int u32;

__device__ __forceinline__ unsigned short f32_to_bf16_rne(float f) {
    u32 u = __float_as_uint(f);
    u = (u + 0x7FFFu + ((u >> 16) & 1u)) >> 16;
    return (unsigned short)u;
}
__device__ __forceinline__ float bf16_to_f32(unsigned short b) {
    return __uint_as_float(((u32)b) << 16);
}

// ===========================================================================
// Fallback path (round-1): edge-parallel atomic scatter + shfl transform.
// ===========================================================================
__global__ void spmm_scatter_kernel(const float* __restrict__ emb,
                                    const int* __restrict__ row,
                                    const int* __restrict__ col,
                                    const float* __restrict__ val,
                                    float* __restrict__ acc,
                                    int n_edges) {
    const int lane = threadIdx.x & 63;
    const int wpb = blockDim.x >> 6;
    const int wib = threadIdx.x >> 6;
    const int total_waves = gridDim.x * wpb;
    for (int e = blockIdx.x * wpb + wib; e < n_edges; e += total_waves) {
        const int r = row[e];
        const int c = col[e];
        const float v = val[e];
        atomicAdd(&acc[(size_t)r * 64 + lane], v * emb[(size_t)c * 64 + lane]);
    }
}

__global__ void transform_leaky_kernel(float* __restrict__ io,
                                       const float* __restrict__ W_u,
                                       const float* __restrict__ W_i,
                                       int n_u_rows, int n_total_rows) {
    __shared__ float Ws[2][64 * 64];
    for (int i = threadIdx.x; i < 64 * 64; i += blockDim.x) {
        Ws[0][i] = W_u[i];
        Ws[1][i] = W_i[i];
    }
    __syncthreads();
    const int lane = threadIdx.x & 63;
    const int wpb = blockDim.x >> 6;
    const int wib = threadIdx.x >> 6;
    const int total_waves = gridDim.x * wpb;
    for (int r = blockIdx.x * wpb + wib; r < n_total_rows; r += total_waves) {
        const float* W = (r < n_u_rows) ? Ws[0] : Ws[1];
        const float hv = io[(size_t)r * 64 + lane];
        float acc = 0.0f;
        #pragma unroll
        for (int k = 0; k < 64; ++k) {
            const float hk = __shfl(hv, k, 64);
            acc = fmaf(hk, W[k * 64 + lane], acc);
        }
        io[(size_t)r * 64 + lane] = acc > 0.0f ? acc : NEG_SLOPE * acc;
    }
}

// ===========================================================================
// FUSED: hist (blocks 0..HB-1) + pre-transform (blocks HB..). Independent
// outputs (cnt vs Ybf); hist blocks first so their latency-bound atomics
// overlap pretransform's FMA-heavy blocks on the same CUs.
// ===========================================================================
#define PT_ROWS 64
#define HB 256  // hist blocks

__global__ void fused_pt_hist_kernel(const float* __restrict__ uemb,
                                     const float* __restrict__ iemb,
                                     const float* __restrict__ W_u,
                                     const float* __restrict__ W_i,
                                     unsigned short* __restrict__ Ybf,
                                     int n_u, int n_i, int tiles_u,
                                     const int* __restrict__ u_row, int e_u,
                                     const int* __restrict__ i_row, int e_i,
                                     int* __restrict__ counts, int nfb) {
    __shared__ union {
        struct { float Ws[64 * 64]; float hs[PT_ROWS][68]; } pt;  // 33792 B
        int lh[8448];
    } sm;

    if (blockIdx.x < HB) {
        // ---------------- histogram role ----------------
        int* lh = sm.lh;
        for (int i = threadIdx.x; i < nfb; i += blockDim.x) lh[i] = 0;
        __syncthreads();
        const int tid = blockIdx.x * blockDim.x + threadIdx.x;
        const int stride = HB * blockDim.x;

        const int n41 = e_u >> 2;
        for (int g = tid; g < n41; g += stride) {
            const int4 r4 = ((const int4*)u_row)[g];
            atomicAdd(&lh[r4.x >> 6], 1);
            atomicAdd(&lh[r4.y >> 6], 1);
            atomicAdd(&lh[r4.z >> 6], 1);
            atomicAdd(&lh[r4.w >> 6], 1);
        }
        for (int e = (n41 << 2) + tid; e < e_u; e += stride)
            atomicAdd(&lh[u_row[e] >> 6], 1);

        const int n42 = e_i >> 2;
        for (int g = tid; g < n42; g += stride) {
            const int4 r4 = ((const int4*)i_row)[g];
            atomicAdd(&lh[(n_u + r4.x) >> 6], 1);
            atomicAdd(&lh[(n_u + r4.y) >> 6], 1);
            atomicAdd(&lh[(n_u + r4.z) >> 6], 1);
            atomicAdd(&lh[(n_u + r4.w) >> 6], 1);
        }
        for (int e = (n42 << 2) + tid; e < e_i; e += stride)
            atomicAdd(&lh[(n_u + i_row[e]) >> 6], 1);

        __syncthreads();
        for (int i = threadIdx.x; i < nfb; i += blockDim.x) {
            const int c = lh[i];
            if (c) atomicAdd(&counts[i], c);
        }
        return;
    }

    // ---------------- pre-transform role ----------------
    const int tile = blockIdx.x - HB;
    const bool is_u = tile < tiles_u;
    const float* __restrict__ emb = is_u ? uemb : iemb;
    const float* __restrict__ W = is_u ? W_u : W_i;
    const int lt = is_u ? tile : tile - tiles_u;
    const int nr = is_u ? n_u : n_i;
    const int base = lt * PT_ROWS;
    const int rows_here = min(PT_ROWS, nr - base);
    const size_t ybase = (is_u ? (size_t)base : (size_t)n_u + base) * 64;

    const int lane = threadIdx.x & 63;
    const int wid  = threadIdx.x >> 6;
    const int rsub = lane >> 4;
    const int jg   = lane & 15;

    {
        const float4* src = (const float4*)W;
        float4* dst = (float4*)sm.pt.Ws;
        for (int i = threadIdx.x; i < 64 * 16; i += blockDim.x) dst[i] = src[i];
    }
    for (int i = threadIdx.x; i < rows_here * 16; i += blockDim.x) {
        const int r = i >> 4, q = i & 15;
        const float4 v = ((const float4*)(emb + (size_t)(base + r) * 64))[q];
        *(float4*)&sm.pt.hs[r][q * 4] = v;
    }
    __syncthreads();

    #pragma unroll
    for (int quad = 0; quad < 4; ++quad) {
        const int r = (wid + quad * 4) * 4 + rsub;
        if (r < rows_here) {
            float ax = 0.f, ay = 0.f, az = 0.f, aw = 0.f;
            #pragma unroll
            for (int kq = 0; kq < 16; ++kq) {
                const float4 h = *(const float4*)&sm.pt.hs[r][kq * 4];
                const float4 w0 = *(const float4*)&sm.pt.Ws[(kq * 4 + 0) * 64 + jg * 4];
                const float4 w1 = *(const float4*)&sm.pt.Ws[(kq * 4 + 1) * 64 + jg * 4];
                const float4 w2 = *(const float4*)&sm.pt.Ws[(kq * 4 + 2) * 64 + jg * 4];
                const float4 w3 = *(const float4*)&sm.pt.Ws[(kq * 4 + 3) * 64 + jg * 4];
                ax = fmaf(h.x, w0.x, ax); ay = fmaf(h.x, w0.y, ay);
                az = fmaf(h.x, w0.z, az); aw = fmaf(h.x, w0.w, aw);
                ax = fmaf(h.y, w1.x, ax); ay = fmaf(h.y, w1.y, ay);
                az = fmaf(h.y, w1.z, az); aw = fmaf(h.y, w1.w, aw);
                ax = fmaf(h.z, w2.x, ax); ay = fmaf(h.z, w2.y, ay);
                az = fmaf(h.z, w2.z, az); aw = fmaf(h.z, w2.w, aw);
                ax = fmaf(h.w, w3.x, ax); ay = fmaf(h.w, w3.y, ay);
                az = fmaf(h.w, w3.z, az); aw = fmaf(h.w, w3.w, aw);
            }
            ushort4 o;
            o.x = f32_to_bf16_rne(ax);
            o.y = f32_to_bf16_rne(ay);
            o.z = f32_to_bf16_rne(az);
            o.w = f32_to_bf16_rne(aw);
            *(ushort4*)(Ybf + ybase + (size_t)r * 64 + jg * 4) = o;
        }
    }
}

#define FPC 128  // fine buckets (64 rows) per coarse bucket (8192 rows)

// ===========================================================================
// Single-block scan+init (1024 threads): padded exclusive scan of cnt ->
// fstart/gfcur + coarse starts/counts/cursors.
// LDS (dynamic): s[1024] | sfs[nfb+1] | sc[64]
// ===========================================================================
__global__ void scan_init_kernel(const int* __restrict__ cnt, int nfb, int ncb,
                                 int* __restrict__ fstart,
                                 int* __restrict__ gfcur,
                                 int* __restrict__ cstart,
                                 int* __restrict__ ccnt,
                                 int* __restrict__ gcurA) {
    extern __shared__ int smem[];
    int* s   = smem;                    // 1024
    int* sfs = smem + 1024;             // nfb+1
    int* sc  = smem + 1024 + nfb + 1;   // 64

    const int tid = threadIdx.x;
    const int ipt = (nfb + 1023) >> 10;   // <= 8 (guarded host-side)
    if (tid < 64) sc[tid] = 0;
    __syncthreads();

    int loc[8];
    int sum = 0;
    const int b0 = tid * ipt;
    for (int k = 0; k < ipt; ++k) {
        const int i = b0 + k;
        int v = 0;
        if (i < nfb) {
            const int c = cnt[i];
            v = (c + 7) & ~7;                 // 64B-aligned bucket regions
            atomicAdd(&sc[i >> 7], c);        // unpadded coarse sums
        }
        loc[k] = sum;
        sum += v;
    }
    s[tid] = sum;
    __syncthreads();
    for (int off = 1; off < 1024; off <<= 1) {
        int t = (tid >= off) ? s[tid - off] : 0;
        __syncthreads();
        s[tid] += t;
        __syncthreads();
    }
    const int excl = s[tid] - sum;
    for (int k = 0; k < ipt; ++k) {
        const int i = b0 + k;
        if (i < nfb) {
            const int f = excl + loc[k];
            fstart[i] = f;
            gfcur[i] = f;
            sfs[i] = f;
        }
    }
    if (tid == 0) {
        const int tot = s[1023];
        fstart[nfb] = tot;
        sfs[nfb] = tot;
    }
    __syncthreads();

    if (tid < ncb) {
        const int st = sfs[min(tid * FPC, nfb)];
        cstart[tid] = st;
        gcurA[tid] = st;
        ccnt[tid] = sc[tid];
    }
    if (tid == ncb) cstart[ncb] = sfs[nfb];
}

// ===========================================================================
// Pass A (both lists, one launch): tile-wise counting sort into coarse
// buckets (8192 rows). lo = col_global(19b) | (row&8191)<<19 ; hi = val.
// ===========================================================================
#define TA 2048
__global__ void passA2_kernel(const int* __restrict__ u_row,
                              const int* __restrict__ u_col,
                              const float* __restrict__ u_val, int e_u,
                              const int* __restrict__ i_row,
                              const int* __restrict__ i_col,
                              const float* __restrict__ i_val, int e_i,
                              int n_u, int tiles_u,
                              int* __restrict__ gcurA,
                              int2* __restrict__ stagA, int ncb) {
    __shared__ int elo[TA], ehi[TA], ebk[TA];
    __shared__ int cnt[64], base[64], gb[64];
    const int tid = threadIdx.x;
    const int bid = blockIdx.x;

    const bool is_u = bid < tiles_u;
    const int* __restrict__ rows = is_u ? u_row : i_row;
    const int* __restrict__ cols = is_u ? u_col : i_col;
    const float* __restrict__ vals = is_u ? u_val : i_val;
    const int n_edges = is_u ? e_u : e_i;
    const int off = is_u ? 0 : n_u;
    const int tstart = (is_u ? bid : bid - tiles_u) * TA;
    const int tn = min(TA, n_edges - tstart);

    if (tid < 64) cnt[tid] = 0;
    __syncthreads();

    int mylo[8], myhi[8], mycb[8], myrk[8];
    #pragma unroll
    for (int j = 0; j < 8; ++j) {
        const int t = tid + j * 256;
        mycb[j] = -1;
        if (t < tn) {
            const int e = tstart + t;
            const int r = off + rows[e];
            const int c = off + cols[e];
            const int cb = r >> 13;
            mylo[j] = c | ((r & 8191) << 19);
            myhi[j] = __float_as_int(vals[e]);
            mycb[j] = cb;
            myrk[j] = atomicAdd(&cnt[cb], 1);
        }
    }
    __syncthreads();
    if (tid == 0) {
        int acc = 0;
        for (int b = 0; b < ncb; ++b) { base[b] = acc; acc += cnt[b]; }
    }
    if (tid < ncb) gb[tid] = (cnt[tid] > 0) ? atomicAdd(&gcurA[tid], cnt[tid]) : 0;
    __syncthreads();
    #pragma unroll
    for (int j = 0; j < 8; ++j) {
        if (mycb[j] >= 0) {
            const int pos = base[mycb[j]] + myrk[j];
            elo[pos] = mylo[j];
            ehi[pos] = myhi[j];
            ebk[pos] = mycb[j];
        }
    }
    __syncthreads();
    #pragma unroll
    for (int j = 0; j < 8; ++j) {
        const int t = tid + j * 256;
        if (t < tn) {
            const int b = ebk[t];
            stagA[gb[b] + (t - base[b])] = make_int2(elo[t], ehi[t]);
        }
    }
}

// ===========================================================================
// Pass B: within each coarse region, counting sort into 128 fine buckets
// (64 rows each). fine-in-coarse = (u32)lo >> 25 (7 bits).
// ===========================================================================
#define TB 2048
#define KB 64
__global__ void passB_kernel(const int2* __restrict__ stagA,
                             const int* __restrict__ cstart,
                             const int* __restrict__ ccnt,
                             int* __restrict__ gfcur,
                             int2* __restrict__ stagB, int nfb) {
    __shared__ int elo[TB], ehi[TB];
    __shared__ int cnt[FPC], base[FPC], gb[FPC];
    const int tid = threadIdx.x;
    const int cb = blockIdx.x / KB;
    const int k  = blockIdx.x % KB;
    const int s = cstart[cb];
    const int n = ccnt[cb];
    const int chunk = (n + KB - 1) / KB;
    const int lo_i = k * chunk;
    const int hi_i = min(n, lo_i + chunk);

    for (int t0 = lo_i; t0 < hi_i; t0 += TB) {
        const int tn = min(TB, hi_i - t0);

        __syncthreads();
        if (tid < FPC) cnt[tid] = 0;
        __syncthreads();

        int mylo[8], myhi[8], myfb[8], myrk[8];
        #pragma unroll
        for (int j = 0; j < 8; ++j) {
            const int t = tid + j * 256;
            myfb[j] = -1;
            if (t < tn) {
                const int2 e = stagA[s + t0 + t];
                const int f = (int)(((u32)e.x) >> 25);
                mylo[j] = e.x;
                myhi[j] = e.y;
                myfb[j] = f;
                myrk[j] = atomicAdd(&cnt[f], 1);
            }
        }
        __syncthreads();
        if (tid == 0) {
            int acc = 0;
            for (int b = 0; b < FPC; ++b) { base[b] = acc; acc += cnt[b]; }
        }
        if (tid < FPC) {
            const int idx = cb * FPC + tid;
            gb[tid] = (idx < nfb && cnt[tid] > 0) ? atomicAdd(&gfcur[idx], cnt[tid]) : 0;
        }
        __syncthreads();
        #pragma unroll
        for (int j = 0; j < 8; ++j) {
            if (myfb[j] >= 0) {
                const int pos = base[myfb[j]] + myrk[j];
                elo[pos] = mylo[j];
                ehi[pos] = myhi[j];
            }
        }
        __syncthreads();
        #pragma unroll
        for (int j = 0; j < 8; ++j) {
            const int t = tid + j * 256;
            if (t < tn) {
                const int b = (int)(((u32)elo[t]) >> 25);
                stagB[gb[b] + (t - base[b])] = make_int2(elo[t], ehi[t]);
            }
        }
    }
}

// ===========================================================================
// Pass C (exact R7 body): one block per 64-row fine bucket. In-LDS counting
// sort by exact row (two 32-row halves), then per-wave REGISTER-accumulated
// row gather, one coalesced 256B store per row.
// ===========================================================================
#define EC 2048
__global__ void passC_kernel(const unsigned short* __restrict__ Ybf,
                             const int2* __restrict__ stagB,
                             const int* __restrict__ fstart,
                             const int* __restrict__ cnt,
                             float* __restrict__ out, int n_rows) {
    __shared__ int2 eds[EC];
    __shared__ int rcnt[64];
    __shared__ int rptr[65];
    const int tid = threadIdx.x;
    const int lane = tid & 63;
    const int wid = tid >> 6;
    const int fb = blockIdx.x;
    const int s = fstart[fb];
    const int n = cnt[fb];
    const int row0 = fb << 6;
    const int rows_here = min(64, n_rows - row0);

    if (n == 0) {  // leaky(0) = 0, but out must still be written
        for (int i = tid; i < rows_here * 16; i += 256)
            ((float4*)(out + (size_t)row0 * 64))[i] = make_float4(0.f, 0.f, 0.f, 0.f);
        return;
    }

    if (tid < 64) rcnt[tid] = 0;
    __syncthreads();

    // rank all bucket edges by exact row (6 bits at lo>>19)
    int mylo[8], myhi[8], myrb[8], myrk[8];
    #pragma unroll
    for (int j = 0; j < 8; ++j) {
        const int t = tid + j * 256;
        myrb[j] = -1;
        if (t < n && t < EC) {
            const int2 e = stagB[s + t];
            const int rb = (e.x >> 19) & 63;
            mylo[j] = e.x;
            myhi[j] = e.y;
            myrb[j] = rb;
            myrk[j] = atomicAdd(&rcnt[rb], 1);
        }
    }
    __syncthreads();
    if (tid == 0) {
        int acc = 0;
        for (int b = 0; b < 64; ++b) { rptr[b] = acc; acc += rcnt[b]; }
        rptr[64] = acc;
    }
    __syncthreads();

    for (int h = 0; h < 2; ++h) {
        const int hbase = rptr[h * 32];
        #pragma unroll
        for (int j = 0; j < 8; ++j) {
            const int rb = myrb[j];
            if (rb >= h * 32 && rb < (h + 1) * 32) {
                const int pos = rptr[rb] + myrk[j] - hbase;
                if (pos < EC) eds[pos] = make_int2(mylo[j], myhi[j]);
            }
        }
        __syncthreads();
        for (int rr = 0; rr < 8; ++rr) {
            const int rl = h * 32 + wid * 8 + rr;
            const int js = rptr[rl] - hbase;
            const int je = rptr[rl + 1] - hbase;
            float a0 = 0.f, a1 = 0.f, a2 = 0.f, a3 = 0.f;
            int j = js;
            for (; j + 4 <= je; j += 4) {
                const int2 e0 = eds[j];
                const int2 e1 = eds[j + 1];
                const int2 e2 = eds[j + 2];
                const int2 e3 = eds[j + 3];
                const float y0 = bf16_to_f32(Ybf[(size_t)(e0.x & 0x7FFFF) * 64 + lane]);
                const float y1 = bf16_to_f32(Ybf[(size_t)(e1.x & 0x7FFFF) * 64 + lane]);
                const float y2 = bf16_to_f32(Ybf[(size_t)(e2.x & 0x7FFFF) * 64 + lane]);
                const float y3 = bf16_to_f32(Ybf[(size_t)(e3.x & 0x7FFFF) * 64 + lane]);
                a0 = fmaf(__int_as_float(e0.y), y0, a0);
                a1 = fmaf(__int_as_float(e1.y), y1, a1);
                a2 = fmaf(__int_as_float(e2.y), y2, a2);
                a3 = fmaf(__int_as_float(e3.y), y3, a3);
            }
            for (; j < je; ++j) {
                const int2 e0 = eds[j];
                a0 = fmaf(__int_as_float(e0.y),
                          bf16_to_f32(Ybf[(size_t)(e0.x & 0x7FFFF) * 64 + lane]), a0);
            }
            const int rgl = row0 + rl;
            if (rgl < n_rows) {
                const float a = (a0 + a1) + (a2 + a3);
                out[(size_t)rgl * 64 + lane] = a > 0.f ? a : NEG_SLOPE * a;
            }
        }
        __syncthreads();
    }
}

// ===========================================================================
extern "C" void kernel_launch(void* const* d_in, const int* in_sizes, int n_in,
                              void* d_out, int out_size, void* d_ws, size_t ws_size,
                              hipStream_t stream) {
    const float* users_emb = (const float*)d_in[0];
    const float* items_emb = (const float*)d_in[1];
    const int*   u_row     = (const int*)d_in[2];
    const int*   u_col     = (const int*)d_in[3];
    const float* u_val     = (const float*)d_in[4];
    const int*   i_row     = (const int*)d_in[5];
    const int*   i_col     = (const int*)d_in[6];
    const float* i_val     = (const float*)d_in[7];
    const float* W_u       = (const float*)d_in[8];
    const float* W_i       = (const float*)d_in[9];

    const int n_u = in_sizes[0] / 64;           // 100000
    const int n_i = in_sizes[1] / 64;           // 200000
    const int e_u = in_sizes[2];                // 1.6M
    const int e_i = in_sizes[5];                // 3.2M
    const int n_rows = n_u + n_i;               // 300000
    const long long E = (long long)e_u + e_i;   // 4.8M

    float* out = (float*)d_out;

    const int BLK = 256;
    const int nfb = (n_rows + 63) >> 6;         // 4688 fine buckets (64 rows)
    const int ncb = (n_rows + 8191) >> 13;      // 37 coarse buckets (8192 rows)
    const long long EPAD = E + (long long)nfb * 8;

    // Workspace layout (word offsets, 4-word aligned sections):
    size_t off = 0;
    #define ALIGN4 off = (off + 3) & ~(size_t)3
    const size_t o_cnt    = off;  off += (size_t)nfb;        ALIGN4;
    const size_t o_fstart = off;  off += (size_t)nfb + 1;    ALIGN4;
    const size_t o_cstart = off;  off += (size_t)ncb + 1;    ALIGN4;
    const size_t o_ccnt   = off;  off += (size_t)ncb;        ALIGN4;
    const size_t o_gcurA  = off;  off += (size_t)ncb;        ALIGN4;
    const size_t o_gfcur  = off;  off += (size_t)nfb;        ALIGN4;
    const size_t o_Y      = off;  off += (size_t)n_rows * 32; ALIGN4;
    const size_t o_stagA  = off;  off += (size_t)EPAD * 2;   ALIGN4;
    const size_t o_stagB  = off;  off += (size_t)EPAD * 2;
    const size_t need_bytes = off * 4;

    if (ws_size >= need_bytes && nfb <= 8192 && ncb <= 63) {
        int*            cnt    = (int*)d_ws + o_cnt;
        int*            fstart = (int*)d_ws + o_fstart;
        int*            cstart = (int*)d_ws + o_cstart;
        int*            ccnt   = (int*)d_ws + o_ccnt;
        int*            gcurA  = (int*)d_ws + o_gcurA;
        int*            gfcur  = (int*)d_ws + o_gfcur;
        unsigned short* Ybf    = (unsigned short*)((int*)d_ws + o_Y);
        int2*           stagA  = (int2*)((int*)d_ws + o_stagA);
        int2*           stagB  = (int2*)((int*)d_ws + o_stagB);

        // 1) fused hist + pre-transform (independent outputs)
        hipMemsetAsync(cnt, 0, (size_t)nfb * 4, stream);
        const int tiles_u_pt = (n_u + PT_ROWS - 1) / PT_ROWS;
        const int tiles_i_pt = (n_i + PT_ROWS - 1) / PT_ROWS;
        fused_pt_hist_kernel<<<HB + tiles_u_pt + tiles_i_pt, BLK, 0, stream>>>(
            users_emb, items_emb, W_u, W_i, Ybf, n_u, n_i, tiles_u_pt,
            u_row, e_u, i_row, e_i, cnt, nfb);

        // 2) scan + all cursor/coarse init in ONE single-block kernel
        const size_t si_lds = (size_t)(1024 + nfb + 1 + 64) * 4;
        scan_init_kernel<<<1, 1024, si_lds, stream>>>(cnt, nfb, ncb, fstart,
                                                      gfcur, cstart, ccnt, gcurA);

        // 3) pass A: coarse binning (both lists, one launch)
        const int tiles_u_a = (e_u + TA - 1) / TA;
        const int tiles_i_a = (e_i + TA - 1) / TA;
        passA2_kernel<<<tiles_u_a + tiles_i_a, BLK, 0, stream>>>(
            u_row, u_col, u_val, e_u, i_row, i_col, i_val, e_i,
            n_u, tiles_u_a, gcurA, stagA, ncb);

        // 4) pass B: fine binning (128 bins per coarse)
        passB_kernel<<<ncb * KB, BLK, 0, stream>>>(stagA, cstart, ccnt,
                                                   gfcur, stagB, nfb);

        // 5) pass C: in-LDS row sort + register gather + coalesced store
        passC_kernel<<<nfb, BLK, 0, stream>>>(Ybf, stagB, fstart, cnt, out, n_rows);
    } else {
        // Fallback: atomic scatter + shfl transform (round-1 path, fp32)
        float* out_u = out;
        float* out_i = out + (size_t)n_u * 64;
        hipMemsetAsync(d_out, 0, (size_t)out_size * sizeof(float), stream);
        const int WPB = BLK / 64;
        int grid_u = (e_u + WPB - 1) / WPB;
        int grid_i = (e_i + WPB - 1) / WPB;
        const int SCAP = 256 * 8;
        if (grid_u > SCAP) grid_u = SCAP;
        if (grid_i > SCAP) grid_i = SCAP;
        spmm_scatter_kernel<<<grid_u, BLK, 0, stream>>>(users_emb, u_row, u_col, u_val, out_u, e_u);
        spmm_scatter_kernel<<<grid_i, BLK, 0, stream>>>(items_emb, i_row, i_col, i_val, out_i, e_i);
        int grid_t = (n_rows + WPB - 1) / WPB;
        if (grid_t > 2048) grid_t = 2048;
        transform_leaky_kernel<<<grid_t, BLK, 0, stream>>>(out, W_u, W_i, n_u, n_rows);
    }
}

// Round 10
// 408.068 us; speedup vs baseline: 1.0007x; 1.0007x over previous
//
#include <hip/hip_runtime.h>

#define NEG_SLOPE 0.2f

typedef unsigned int u32;

__device__ __forceinline__ unsigned short f32_to_bf16_rne(float f) {
    u32 u = __float_as_uint(f);
    u = (u + 0x7FFFu + ((u >> 16) & 1u)) >> 16;
    return (unsigned short)u;
}
__device__ __forceinline__ float bf16_to_f32(unsigned short b) {
    return __uint_as_float(((u32)b) << 16);
}

// ===========================================================================
// Fallback path (round-1): edge-parallel atomic scatter + shfl transform.
// ===========================================================================
__global__ void spmm_scatter_kernel(const float* __restrict__ emb,
                                    const int* __restrict__ row,
                                    const int* __restrict__ col,
                                    const float* __restrict__ val,
                                    float* __restrict__ acc,
                                    int n_edges) {
    const int lane = threadIdx.x & 63;
    const int wpb = blockDim.x >> 6;
    const int wib = threadIdx.x >> 6;
    const int total_waves = gridDim.x * wpb;
    for (int e = blockIdx.x * wpb + wib; e < n_edges; e += total_waves) {
        const int r = row[e];
        const int c = col[e];
        const float v = val[e];
        atomicAdd(&acc[(size_t)r * 64 + lane], v * emb[(size_t)c * 64 + lane]);
    }
}

__global__ void transform_leaky_kernel(float* __restrict__ io,
                                       const float* __restrict__ W_u,
                                       const float* __restrict__ W_i,
                                       int n_u_rows, int n_total_rows) {
    __shared__ float Ws[2][64 * 64];
    for (int i = threadIdx.x; i < 64 * 64; i += blockDim.x) {
        Ws[0][i] = W_u[i];
        Ws[1][i] = W_i[i];
    }
    __syncthreads();
    const int lane = threadIdx.x & 63;
    const int wpb = blockDim.x >> 6;
    const int wib = threadIdx.x >> 6;
    const int total_waves = gridDim.x * wpb;
    for (int r = blockIdx.x * wpb + wib; r < n_total_rows; r += total_waves) {
        const float* W = (r < n_u_rows) ? Ws[0] : Ws[1];
        const float hv = io[(size_t)r * 64 + lane];
        float acc = 0.0f;
        #pragma unroll
        for (int k = 0; k < 64; ++k) {
            const float hk = __shfl(hv, k, 64);
            acc = fmaf(hk, W[k * 64 + lane], acc);
        }
        io[(size_t)r * 64 + lane] = acc > 0.0f ? acc : NEG_SLOPE * acc;
    }
}

// ===========================================================================
// FUSED: hist (blocks 0..HB-1) + pre-transform (blocks HB..). Independent
// outputs (cnt vs Ybf); hist blocks first so their latency-bound atomics
// overlap pretransform's FMA-heavy blocks on the same CUs.
// ===========================================================================
#define PT_ROWS 64
#define HB 256  // hist blocks

__global__ void fused_pt_hist_kernel(const float* __restrict__ uemb,
                                     const float* __restrict__ iemb,
                                     const float* __restrict__ W_u,
                                     const float* __restrict__ W_i,
                                     unsigned short* __restrict__ Ybf,
                                     int n_u, int n_i, int tiles_u,
                                     const int* __restrict__ u_row, int e_u,
                                     const int* __restrict__ i_row, int e_i,
                                     int* __restrict__ counts, int nfb) {
    __shared__ union {
        struct { float Ws[64 * 64]; float hs[PT_ROWS][68]; } pt;  // 33792 B
        int lh[8448];
    } sm;

    if (blockIdx.x < HB) {
        // ---------------- histogram role ----------------
        int* lh = sm.lh;
        for (int i = threadIdx.x; i < nfb; i += blockDim.x) lh[i] = 0;
        __syncthreads();
        const int tid = blockIdx.x * blockDim.x + threadIdx.x;
        const int stride = HB * blockDim.x;

        const int n41 = e_u >> 2;
        for (int g = tid; g < n41; g += stride) {
            const int4 r4 = ((const int4*)u_row)[g];
            atomicAdd(&lh[r4.x >> 6], 1);
            atomicAdd(&lh[r4.y >> 6], 1);
            atomicAdd(&lh[r4.z >> 6], 1);
            atomicAdd(&lh[r4.w >> 6], 1);
        }
        for (int e = (n41 << 2) + tid; e < e_u; e += stride)
            atomicAdd(&lh[u_row[e] >> 6], 1);

        const int n42 = e_i >> 2;
        for (int g = tid; g < n42; g += stride) {
            const int4 r4 = ((const int4*)i_row)[g];
            atomicAdd(&lh[(n_u + r4.x) >> 6], 1);
            atomicAdd(&lh[(n_u + r4.y) >> 6], 1);
            atomicAdd(&lh[(n_u + r4.z) >> 6], 1);
            atomicAdd(&lh[(n_u + r4.w) >> 6], 1);
        }
        for (int e = (n42 << 2) + tid; e < e_i; e += stride)
            atomicAdd(&lh[(n_u + i_row[e]) >> 6], 1);

        __syncthreads();
        for (int i = threadIdx.x; i < nfb; i += blockDim.x) {
            const int c = lh[i];
            if (c) atomicAdd(&counts[i], c);
        }
        return;
    }

    // ---------------- pre-transform role ----------------
    const int tile = blockIdx.x - HB;
    const bool is_u = tile < tiles_u;
    const float* __restrict__ emb = is_u ? uemb : iemb;
    const float* __restrict__ W = is_u ? W_u : W_i;
    const int lt = is_u ? tile : tile - tiles_u;
    const int nr = is_u ? n_u : n_i;
    const int base = lt * PT_ROWS;
    const int rows_here = min(PT_ROWS, nr - base);
    const size_t ybase = (is_u ? (size_t)base : (size_t)n_u + base) * 64;

    const int lane = threadIdx.x & 63;
    const int wid  = threadIdx.x >> 6;
    const int rsub = lane >> 4;
    const int jg   = lane & 15;

    {
        const float4* src = (const float4*)W;
        float4* dst = (float4*)sm.pt.Ws;
        for (int i = threadIdx.x; i < 64 * 16; i += blockDim.x) dst[i] = src[i];
    }
    for (int i = threadIdx.x; i < rows_here * 16; i += blockDim.x) {
        const int r = i >> 4, q = i & 15;
        const float4 v = ((const float4*)(emb + (size_t)(base + r) * 64))[q];
        *(float4*)&sm.pt.hs[r][q * 4] = v;
    }
    __syncthreads();

    #pragma unroll
    for (int quad = 0; quad < 4; ++quad) {
        const int r = (wid + quad * 4) * 4 + rsub;
        if (r < rows_here) {
            float ax = 0.f, ay = 0.f, az = 0.f, aw = 0.f;
            #pragma unroll
            for (int kq = 0; kq < 16; ++kq) {
                const float4 h = *(const float4*)&sm.pt.hs[r][kq * 4];
                const float4 w0 = *(const float4*)&sm.pt.Ws[(kq * 4 + 0) * 64 + jg * 4];
                const float4 w1 = *(const float4*)&sm.pt.Ws[(kq * 4 + 1) * 64 + jg * 4];
                const float4 w2 = *(const float4*)&sm.pt.Ws[(kq * 4 + 2) * 64 + jg * 4];
                const float4 w3 = *(const float4*)&sm.pt.Ws[(kq * 4 + 3) * 64 + jg * 4];
                ax = fmaf(h.x, w0.x, ax); ay = fmaf(h.x, w0.y, ay);
                az = fmaf(h.x, w0.z, az); aw = fmaf(h.x, w0.w, aw);
                ax = fmaf(h.y, w1.x, ax); ay = fmaf(h.y, w1.y, ay);
                az = fmaf(h.y, w1.z, az); aw = fmaf(h.y, w1.w, aw);
                ax = fmaf(h.z, w2.x, ax); ay = fmaf(h.z, w2.y, ay);
                az = fmaf(h.z, w2.z, az); aw = fmaf(h.z, w2.w, aw);
                ax = fmaf(h.w, w3.x, ax); ay = fmaf(h.w, w3.y, ay);
                az = fmaf(h.w, w3.z, az); aw = fmaf(h.w, w3.w, aw);
            }
            ushort4 o;
            o.x = f32_to_bf16_rne(ax);
            o.y = f32_to_bf16_rne(ay);
            o.z = f32_to_bf16_rne(az);
            o.w = f32_to_bf16_rne(aw);
            *(ushort4*)(Ybf + ybase + (size_t)r * 64 + jg * 4) = o;
        }
    }
}

#define FPC 128  // fine buckets (64 rows) per coarse bucket (8192 rows)

// ===========================================================================
// Single-block scan+init (1024 threads): padded exclusive scan of cnt ->
// fstart/gfcur + coarse starts/counts/cursors.
// LDS (dynamic): s[1024] | sfs[nfb+1] | sc[64]
// ===========================================================================
__global__ void scan_init_kernel(const int* __restrict__ cnt, int nfb, int ncb,
                                 int* __restrict__ fstart,
                                 int* __restrict__ gfcur,
                                 int* __restrict__ cstart,
                                 int* __restrict__ ccnt,
                                 int* __restrict__ gcurA) {
    extern __shared__ int smem[];
    int* s   = smem;                    // 1024
    int* sfs = smem + 1024;             // nfb+1
    int* sc  = smem + 1024 + nfb + 1;   // 64

    const int tid = threadIdx.x;
    const int ipt = (nfb + 1023) >> 10;   // <= 8 (guarded host-side)
    if (tid < 64) sc[tid] = 0;
    __syncthreads();

    int loc[8];
    int sum = 0;
    const int b0 = tid * ipt;
    for (int k = 0; k < ipt; ++k) {
        const int i = b0 + k;
        int v = 0;
        if (i < nfb) {
            const int c = cnt[i];
            v = (c + 7) & ~7;                 // 64B-aligned bucket regions
            atomicAdd(&sc[i >> 7], c);        // unpadded coarse sums
        }
        loc[k] = sum;
        sum += v;
    }
    s[tid] = sum;
    __syncthreads();
    for (int off = 1; off < 1024; off <<= 1) {
        int t = (tid >= off) ? s[tid - off] : 0;
        __syncthreads();
        s[tid] += t;
        __syncthreads();
    }
    const int excl = s[tid] - sum;
    for (int k = 0; k < ipt; ++k) {
        const int i = b0 + k;
        if (i < nfb) {
            const int f = excl + loc[k];
            fstart[i] = f;
            gfcur[i] = f;
            sfs[i] = f;
        }
    }
    if (tid == 0) {
        const int tot = s[1023];
        fstart[nfb] = tot;
        sfs[nfb] = tot;
    }
    __syncthreads();

    if (tid < ncb) {
        const int st = sfs[min(tid * FPC, nfb)];
        cstart[tid] = st;
        gcurA[tid] = st;
        ccnt[tid] = sc[tid];
    }
    if (tid == ncb) cstart[ncb] = sfs[nfb];
}

// ===========================================================================
// Pass A (both lists, one launch): tile-wise counting sort into coarse
// buckets (8192 rows). lo = col_global(19b) | (row&8191)<<19 ; hi = val.
// ===========================================================================
#define TA 2048
__global__ void passA2_kernel(const int* __restrict__ u_row,
                              const int* __restrict__ u_col,
                              const float* __restrict__ u_val, int e_u,
                              const int* __restrict__ i_row,
                              const int* __restrict__ i_col,
                              const float* __restrict__ i_val, int e_i,
                              int n_u, int tiles_u,
                              int* __restrict__ gcurA,
                              int2* __restrict__ stagA, int ncb) {
    __shared__ int elo[TA], ehi[TA], ebk[TA];
    __shared__ int cnt[64], base[64], gb[64];
    const int tid = threadIdx.x;
    const int bid = blockIdx.x;

    const bool is_u = bid < tiles_u;
    const int* __restrict__ rows = is_u ? u_row : i_row;
    const int* __restrict__ cols = is_u ? u_col : i_col;
    const float* __restrict__ vals = is_u ? u_val : i_val;
    const int n_edges = is_u ? e_u : e_i;
    const int off = is_u ? 0 : n_u;
    const int tstart = (is_u ? bid : bid - tiles_u) * TA;
    const int tn = min(TA, n_edges - tstart);

    if (tid < 64) cnt[tid] = 0;
    __syncthreads();

    int mylo[8], myhi[8], mycb[8], myrk[8];
    #pragma unroll
    for (int j = 0; j < 8; ++j) {
        const int t = tid + j * 256;
        mycb[j] = -1;
        if (t < tn) {
            const int e = tstart + t;
            const int r = off + rows[e];
            const int c = off + cols[e];
            const int cb = r >> 13;
            mylo[j] = c | ((r & 8191) << 19);
            myhi[j] = __float_as_int(vals[e]);
            mycb[j] = cb;
            myrk[j] = atomicAdd(&cnt[cb], 1);
        }
    }
    __syncthreads();
    if (tid == 0) {
        int acc = 0;
        for (int b = 0; b < ncb; ++b) { base[b] = acc; acc += cnt[b]; }
    }
    if (tid < ncb) gb[tid] = (cnt[tid] > 0) ? atomicAdd(&gcurA[tid], cnt[tid]) : 0;
    __syncthreads();
    #pragma unroll
    for (int j = 0; j < 8; ++j) {
        if (mycb[j] >= 0) {
            const int pos = base[mycb[j]] + myrk[j];
            elo[pos] = mylo[j];
            ehi[pos] = myhi[j];
            ebk[pos] = mycb[j];
        }
    }
    __syncthreads();
    #pragma unroll
    for (int j = 0; j < 8; ++j) {
        const int t = tid + j * 256;
        if (t < tn) {
            const int b = ebk[t];
            stagA[gb[b] + (t - base[b])] = make_int2(elo[t], ehi[t]);
        }
    }
}

// ===========================================================================
// Pass B: within each coarse region, counting sort into 128 fine buckets
// (64 rows each). fine-in-coarse = (u32)lo >> 25 (7 bits).
// ===========================================================================
#define TB 2048
#define KB 64
__global__ void passB_kernel(const int2* __restrict__ stagA,
                             const int* __restrict__ cstart,
                             const int* __restrict__ ccnt,
                             int* __restrict__ gfcur,
                             int2* __restrict__ stagB, int nfb) {
    __shared__ int elo[TB], ehi[TB];
    __shared__ int cnt[FPC], base[FPC], gb[FPC];
    const int tid = threadIdx.x;
    const int cb = blockIdx.x / KB;
    const int k  = blockIdx.x % KB;
    const int s = cstart[cb];
    const int n = ccnt[cb];
    const int chunk = (n + KB - 1) / KB;
    const int lo_i = k * chunk;
    const int hi_i = min(n, lo_i + chunk);

    for (int t0 = lo_i; t0 < hi_i; t0 += TB) {
        const int tn = min(TB, hi_i - t0);

        __syncthreads();
        if (tid < FPC) cnt[tid] = 0;
        __syncthreads();

        int mylo[8], myhi[8], myfb[8], myrk[8];
        #pragma unroll
        for (int j = 0; j < 8; ++j) {
            const int t = tid + j * 256;
            myfb[j] = -1;
            if (t < tn) {
                const int2 e = stagA[s + t0 + t];
                const int f = (int)(((u32)e.x) >> 25);
                mylo[j] = e.x;
                myhi[j] = e.y;
                myfb[j] = f;
                myrk[j] = atomicAdd(&cnt[f], 1);
            }
        }
        __syncthreads();
        if (tid == 0) {
            int acc = 0;
            for (int b = 0; b < FPC; ++b) { base[b] = acc; acc += cnt[b]; }
        }
        if (tid < FPC) {
            const int idx = cb * FPC + tid;
            gb[tid] = (idx < nfb && cnt[tid] > 0) ? atomicAdd(&gfcur[idx], cnt[tid]) : 0;
        }
        __syncthreads();
        #pragma unroll
        for (int j = 0; j < 8; ++j) {
            if (myfb[j] >= 0) {
                const int pos = base[myfb[j]] + myrk[j];
                elo[pos] = mylo[j];
                ehi[pos] = myhi[j];
            }
        }
        __syncthreads();
        #pragma unroll
        for (int j = 0; j < 8; ++j) {
            const int t = tid + j * 256;
            if (t < tn) {
                const int b = (int)(((u32)elo[t]) >> 25);
                stagB[gb[b] + (t - base[b])] = make_int2(elo[t], ehi[t]);
            }
        }
    }
}

// ===========================================================================
// Pass C (exact R7 body): one block per 64-row fine bucket. In-LDS counting
// sort by exact row (two 32-row halves), then per-wave REGISTER-accumulated
// row gather, one coalesced 256B store per row.
// ===========================================================================
#define EC 2048
__global__ void passC_kernel(const unsigned short* __restrict__ Ybf,
                             const int2* __restrict__ stagB,
                             const int* __restrict__ fstart,
                             const int* __restrict__ cnt,
                             float* __restrict__ out, int n_rows) {
    __shared__ int2 eds[EC];
    __shared__ int rcnt[64];
    __shared__ int rptr[65];
    const int tid = threadIdx.x;
    const int lane = tid & 63;
    const int wid = tid >> 6;
    const int fb = blockIdx.x;
    const int s = fstart[fb];
    const int n = cnt[fb];
    const int row0 = fb << 6;
    const int rows_here = min(64, n_rows - row0);

    if (n == 0) {  // leaky(0) = 0, but out must still be written
        for (int i = tid; i < rows_here * 16; i += 256)
            ((float4*)(out + (size_t)row0 * 64))[i] = make_float4(0.f, 0.f, 0.f, 0.f);
        return;
    }

    if (tid < 64) rcnt[tid] = 0;
    __syncthreads();

    // rank all bucket edges by exact row (6 bits at lo>>19)
    int mylo[8], myhi[8], myrb[8], myrk[8];
    #pragma unroll
    for (int j = 0; j < 8; ++j) {
        const int t = tid + j * 256;
        myrb[j] = -1;
        if (t < n && t < EC) {
            const int2 e = stagB[s + t];
            const int rb = (e.x >> 19) & 63;
            mylo[j] = e.x;
            myhi[j] = e.y;
            myrb[j] = rb;
            myrk[j] = atomicAdd(&rcnt[rb], 1);
        }
    }
    __syncthreads();
    if (tid == 0) {
        int acc = 0;
        for (int b = 0; b < 64; ++b) { rptr[b] = acc; acc += rcnt[b]; }
        rptr[64] = acc;
    }
    __syncthreads();

    for (int h = 0; h < 2; ++h) {
        const int hbase = rptr[h * 32];
        #pragma unroll
        for (int j = 0; j < 8; ++j) {
            const int rb = myrb[j];
            if (rb >= h * 32 && rb < (h + 1) * 32) {
                const int pos = rptr[rb] + myrk[j] - hbase;
                if (pos < EC) eds[pos] = make_int2(mylo[j], myhi[j]);
            }
        }
        __syncthreads();
        for (int rr = 0; rr < 8; ++rr) {
            const int rl = h * 32 + wid * 8 + rr;
            const int js = rptr[rl] - hbase;
            const int je = rptr[rl + 1] - hbase;
            float a0 = 0.f, a1 = 0.f, a2 = 0.f, a3 = 0.f;
            int j = js;
            for (; j + 4 <= je; j += 4) {
                const int2 e0 = eds[j];
                const int2 e1 = eds[j + 1];
                const int2 e2 = eds[j + 2];
                const int2 e3 = eds[j + 3];
                const float y0 = bf16_to_f32(Ybf[(size_t)(e0.x & 0x7FFFF) * 64 + lane]);
                const float y1 = bf16_to_f32(Ybf[(size_t)(e1.x & 0x7FFFF) * 64 + lane]);
                const float y2 = bf16_to_f32(Ybf[(size_t)(e2.x & 0x7FFFF) * 64 + lane]);
                const float y3 = bf16_to_f32(Ybf[(size_t)(e3.x & 0x7FFFF) * 64 + lane]);
                a0 = fmaf(__int_as_float(e0.y), y0, a0);
                a1 = fmaf(__int_as_float(e1.y), y1, a1);
                a2 = fmaf(__int_as_float(e2.y), y2, a2);
                a3 = fmaf(__int_as_float(e3.y), y3, a3);
            }
            for (; j < je; ++j) {
                const int2 e0 = eds[j];
                a0 = fmaf(__int_as_float(e0.y),
                          bf16_to_f32(Ybf[(size_t)(e0.x & 0x7FFFF) * 64 + lane]), a0);
            }
            const int rgl = row0 + rl;
            if (rgl < n_rows) {
                const float a = (a0 + a1) + (a2 + a3);
                out[(size_t)rgl * 64 + lane] = a > 0.f ? a : NEG_SLOPE * a;
            }
        }
        __syncthreads();
    }
}

// ===========================================================================
extern "C" void kernel_launch(void* const* d_in, const int* in_sizes, int n_in,
                              void* d_out, int out_size, void* d_ws, size_t ws_size,
                              hipStream_t stream) {
    const float* users_emb = (const float*)d_in[0];
    const float* items_emb = (const float*)d_in[1];
    const int*   u_row     = (const int*)d_in[2];
    const int*   u_col     = (const int*)d_in[3];
    const float* u_val     = (const float*)d_in[4];
    const int*   i_row     = (const int*)d_in[5];
    const int*   i_col     = (const int*)d_in[6];
    const float* i_val     = (const float*)d_in[7];
    const float* W_u       = (const float*)d_in[8];
    const float* W_i       = (const float*)d_in[9];

    const int n_u = in_sizes[0] / 64;           // 100000
    const int n_i = in_sizes[1] / 64;           // 200000
    const int e_u = in_sizes[2];                // 1.6M
    const int e_i = in_sizes[5];                // 3.2M
    const int n_rows = n_u + n_i;               // 300000
    const long long E = (long long)e_u + e_i;   // 4.8M

    float* out = (float*)d_out;

    const int BLK = 256;
    const int nfb = (n_rows + 63) >> 6;         // 4688 fine buckets (64 rows)
    const int ncb = (n_rows + 8191) >> 13;      // 37 coarse buckets (8192 rows)
    const long long EPAD = E + (long long)nfb * 8;

    // Workspace layout (word offsets, 4-word aligned sections):
    size_t off = 0;
    #define ALIGN4 off = (off + 3) & ~(size_t)3
    const size_t o_cnt    = off;  off += (size_t)nfb;        ALIGN4;
    const size_t o_fstart = off;  off += (size_t)nfb + 1;    ALIGN4;
    const size_t o_cstart = off;  off += (size_t)ncb + 1;    ALIGN4;
    const size_t o_ccnt   = off;  off += (size_t)ncb;        ALIGN4;
    const size_t o_gcurA  = off;  off += (size_t)ncb;        ALIGN4;
    const size_t o_gfcur  = off;  off += (size_t)nfb;        ALIGN4;
    const size_t o_Y      = off;  off += (size_t)n_rows * 32; ALIGN4;
    const size_t o_stagA  = off;  off += (size_t)EPAD * 2;   ALIGN4;
    const size_t o_stagB  = off;  off += (size_t)EPAD * 2;
    const size_t need_bytes = off * 4;

    if (ws_size >= need_bytes && nfb <= 8192 && ncb <= 63) {
        int*            cnt    = (int*)d_ws + o_cnt;
        int*            fstart = (int*)d_ws + o_fstart;
        int*            cstart = (int*)d_ws + o_cstart;
        int*            ccnt   = (int*)d_ws + o_ccnt;
        int*            gcurA  = (int*)d_ws + o_gcurA;
        int*            gfcur  = (int*)d_ws + o_gfcur;
        unsigned short* Ybf    = (unsigned short*)((int*)d_ws + o_Y);
        int2*           stagA  = (int2*)((int*)d_ws + o_stagA);
        int2*           stagB  = (int2*)((int*)d_ws + o_stagB);

        // 1) fused hist + pre-transform (independent outputs)
        hipMemsetAsync(cnt, 0, (size_t)nfb * 4, stream);
        const int tiles_u_pt = (n_u + PT_ROWS - 1) / PT_ROWS;
        const int tiles_i_pt = (n_i + PT_ROWS - 1) / PT_ROWS;
        fused_pt_hist_kernel<<<HB + tiles_u_pt + tiles_i_pt, BLK, 0, stream>>>(
            users_emb, items_emb, W_u, W_i, Ybf, n_u, n_i, tiles_u_pt,
            u_row, e_u, i_row, e_i, cnt, nfb);

        // 2) scan + all cursor/coarse init in ONE single-block kernel
        const size_t si_lds = (size_t)(1024 + nfb + 1 + 64) * 4;
        scan_init_kernel<<<1, 1024, si_lds, stream>>>(cnt, nfb, ncb, fstart,
                                                      gfcur, cstart, ccnt, gcurA);

        // 3) pass A: coarse binning (both lists, one launch)
        const int tiles_u_a = (e_u + TA - 1) / TA;
        const int tiles_i_a = (e_i + TA - 1) / TA;
        passA2_kernel<<<tiles_u_a + tiles_i_a, BLK, 0, stream>>>(
            u_row, u_col, u_val, e_u, i_row, i_col, i_val, e_i,
            n_u, tiles_u_a, gcurA, stagA, ncb);

        // 4) pass B: fine binning (128 bins per coarse)
        passB_kernel<<<ncb * KB, BLK, 0, stream>>>(stagA, cstart, ccnt,
                                                   gfcur, stagB, nfb);

        // 5) pass C: in-LDS row sort + register gather + coalesced store
        passC_kernel<<<nfb, BLK, 0, stream>>>(Ybf, stagB, fstart, cnt, out, n_rows);
    } else {
        // Fallback: atomic scatter + shfl transform (round-1 path, fp32)
        float* out_u = out;
        float* out_i = out + (size_t)n_u * 64;
        hipMemsetAsync(d_out, 0, (size_t)out_size * sizeof(float), stream);
        const int WPB = BLK / 64;
        int grid_u = (e_u + WPB - 1) / WPB;
        int grid_i = (e_i + WPB - 1) / WPB;
        const int SCAP = 256 * 8;
        if (grid_u > SCAP) grid_u = SCAP;
        if (grid_i > SCAP) grid_i = SCAP;
        spmm_scatter_kernel<<<grid_u, BLK, 0, stream>>>(users_emb, u_row, u_col, u_val, out_u, e_u);
        spmm_scatter_kernel<<<grid_i, BLK, 0, stream>>>(items_emb, i_row, i_col, i_val, out_i, e_i);
        int grid_t = (n_rows + WPB - 1) / WPB;
        if (grid_t > 2048) grid_t = 2048;
        transform_leaky_kernel<<<grid_t, BLK, 0, stream>>>(out, W_u, W_i, n_u, n_rows);
    }
}

// Round 11
// 318.022 us; speedup vs baseline: 1.2841x; 1.2831x over previous
//
#include <hip/hip_runtime.h>

#define NEG_SLOPE 0.2f

typedef unsigned int u32;

__device__ __forceinline__ unsigned short f32_to_bf16_rne(float f) {
    u32 u = __float_as_uint(f);
    u = (u + 0x7FFFu + ((u >> 16) & 1u)) >> 16;
    return (unsigned short)u;
}
__device__ __forceinline__ float bf16_to_f32(unsigned short b) {
    return __uint_as_float(((u32)b) << 16);
}

// ===========================================================================
// Fallback path (round-1): edge-parallel atomic scatter + shfl transform.
// ===========================================================================
__global__ void spmm_scatter_kernel(const float* __restrict__ emb,
                                    const int* __restrict__ row,
                                    const int* __restrict__ col,
                                    const float* __restrict__ val,
                                    float* __restrict__ acc,
                                    int n_edges) {
    const int lane = threadIdx.x & 63;
    const int wpb = blockDim.x >> 6;
    const int wib = threadIdx.x >> 6;
    const int total_waves = gridDim.x * wpb;
    for (int e = blockIdx.x * wpb + wib; e < n_edges; e += total_waves) {
        const int r = row[e];
        const int c = col[e];
        const float v = val[e];
        atomicAdd(&acc[(size_t)r * 64 + lane], v * emb[(size_t)c * 64 + lane]);
    }
}

__global__ void transform_leaky_kernel(float* __restrict__ io,
                                       const float* __restrict__ W_u,
                                       const float* __restrict__ W_i,
                                       int n_u_rows, int n_total_rows) {
    __shared__ float Ws[2][64 * 64];
    for (int i = threadIdx.x; i < 64 * 64; i += blockDim.x) {
        Ws[0][i] = W_u[i];
        Ws[1][i] = W_i[i];
    }
    __syncthreads();
    const int lane = threadIdx.x & 63;
    const int wpb = blockDim.x >> 6;
    const int wib = threadIdx.x >> 6;
    const int total_waves = gridDim.x * wpb;
    for (int r = blockIdx.x * wpb + wib; r < n_total_rows; r += total_waves) {
        const float* W = (r < n_u_rows) ? Ws[0] : Ws[1];
        const float hv = io[(size_t)r * 64 + lane];
        float acc = 0.0f;
        #pragma unroll
        for (int k = 0; k < 64; ++k) {
            const float hk = __shfl(hv, k, 64);
            acc = fmaf(hk, W[k * 64 + lane], acc);
        }
        io[(size_t)r * 64 + lane] = acc > 0.0f ? acc : NEG_SLOPE * acc;
    }
}

// ===========================================================================
// Pre-transform (fused u+i): Y = emb @ W, output bf16. Both operands in LDS.
// ===========================================================================
#define PT_ROWS 64
__global__ void pretransform_both_kernel(const float* __restrict__ uemb,
                                         const float* __restrict__ iemb,
                                         const float* __restrict__ W_u,
                                         const float* __restrict__ W_i,
                                         unsigned short* __restrict__ Ybf,
                                         int n_u, int n_i, int tiles_u) {
    __shared__ float Ws[64 * 64];
    __shared__ float hs[PT_ROWS][68];

    const int tile = blockIdx.x;
    const bool is_u = tile < tiles_u;
    const float* __restrict__ emb = is_u ? uemb : iemb;
    const float* __restrict__ W = is_u ? W_u : W_i;
    const int lt = is_u ? tile : tile - tiles_u;
    const int nr = is_u ? n_u : n_i;
    const int base = lt * PT_ROWS;
    const int rows_here = min(PT_ROWS, nr - base);
    const size_t ybase = (is_u ? (size_t)base : (size_t)n_u + base) * 64;

    const int lane = threadIdx.x & 63;
    const int wid  = threadIdx.x >> 6;
    const int rsub = lane >> 4;
    const int jg   = lane & 15;

    {
        const float4* src = (const float4*)W;
        float4* dst = (float4*)Ws;
        for (int i = threadIdx.x; i < 64 * 16; i += blockDim.x) dst[i] = src[i];
    }
    for (int i = threadIdx.x; i < rows_here * 16; i += blockDim.x) {
        const int r = i >> 4, q = i & 15;
        const float4 v = ((const float4*)(emb + (size_t)(base + r) * 64))[q];
        *(float4*)&hs[r][q * 4] = v;
    }
    __syncthreads();

    #pragma unroll
    for (int quad = 0; quad < 4; ++quad) {
        const int r = (wid + quad * 4) * 4 + rsub;
        if (r < rows_here) {
            float ax = 0.f, ay = 0.f, az = 0.f, aw = 0.f;
            #pragma unroll
            for (int kq = 0; kq < 16; ++kq) {
                const float4 h = *(const float4*)&hs[r][kq * 4];
                const float4 w0 = *(const float4*)&Ws[(kq * 4 + 0) * 64 + jg * 4];
                const float4 w1 = *(const float4*)&Ws[(kq * 4 + 1) * 64 + jg * 4];
                const float4 w2 = *(const float4*)&Ws[(kq * 4 + 2) * 64 + jg * 4];
                const float4 w3 = *(const float4*)&Ws[(kq * 4 + 3) * 64 + jg * 4];
                ax = fmaf(h.x, w0.x, ax); ay = fmaf(h.x, w0.y, ay);
                az = fmaf(h.x, w0.z, az); aw = fmaf(h.x, w0.w, aw);
                ax = fmaf(h.y, w1.x, ax); ay = fmaf(h.y, w1.y, ay);
                az = fmaf(h.y, w1.z, az); aw = fmaf(h.y, w1.w, aw);
                ax = fmaf(h.z, w2.x, ax); ay = fmaf(h.z, w2.y, ay);
                az = fmaf(h.z, w2.z, az); aw = fmaf(h.z, w2.w, aw);
                ax = fmaf(h.w, w3.x, ax); ay = fmaf(h.w, w3.y, ay);
                az = fmaf(h.w, w3.z, az); aw = fmaf(h.w, w3.w, aw);
            }
            ushort4 o;
            o.x = f32_to_bf16_rne(ax);
            o.y = f32_to_bf16_rne(ay);
            o.z = f32_to_bf16_rne(az);
            o.w = f32_to_bf16_rne(aw);
            *(ushort4*)(Ybf + ybase + (size_t)r * 64 + jg * 4) = o;
        }
    }
}

// ===========================================================================
// Fine histogram over 64-row buckets, both edge lists in one launch.
// ===========================================================================
__global__ void hist_fine2_kernel(const int* __restrict__ r1, int e1,
                                  const int* __restrict__ r2, int e2,
                                  int off2, int* __restrict__ counts, int nfb) {
    extern __shared__ int lh[];
    for (int i = threadIdx.x; i < nfb; i += blockDim.x) lh[i] = 0;
    __syncthreads();
    const int tid = blockIdx.x * blockDim.x + threadIdx.x;
    const int stride = gridDim.x * blockDim.x;

    const int n41 = e1 >> 2;
    for (int g = tid; g < n41; g += stride) {
        const int4 r4 = ((const int4*)r1)[g];
        atomicAdd(&lh[r4.x >> 6], 1);
        atomicAdd(&lh[r4.y >> 6], 1);
        atomicAdd(&lh[r4.z >> 6], 1);
        atomicAdd(&lh[r4.w >> 6], 1);
    }
    for (int e = (n41 << 2) + tid; e < e1; e += stride)
        atomicAdd(&lh[r1[e] >> 6], 1);

    const int n42 = e2 >> 2;
    for (int g = tid; g < n42; g += stride) {
        const int4 r4 = ((const int4*)r2)[g];
        atomicAdd(&lh[(off2 + r4.x) >> 6], 1);
        atomicAdd(&lh[(off2 + r4.y) >> 6], 1);
        atomicAdd(&lh[(off2 + r4.z) >> 6], 1);
        atomicAdd(&lh[(off2 + r4.w) >> 6], 1);
    }
    for (int e = (n42 << 2) + tid; e < e2; e += stride)
        atomicAdd(&lh[(off2 + r2[e]) >> 6], 1);

    __syncthreads();
    for (int i = threadIdx.x; i < nfb; i += blockDim.x) {
        const int c = lh[i];
        if (c) atomicAdd(&counts[i], c);
    }
}

#define FPC 128  // fine buckets (64 rows) per coarse bucket (8192 rows)

// ===========================================================================
// Single-block scan+init (1024 threads): padded exclusive scan of cnt ->
// fstart/gfcur + coarse starts/counts/cursors.
// LDS (dynamic): s[1024] | sfs[nfb+1] | sc[64]
// ===========================================================================
__global__ void scan_init_kernel(const int* __restrict__ cnt, int nfb, int ncb,
                                 int* __restrict__ fstart,
                                 int* __restrict__ gfcur,
                                 int* __restrict__ cstart,
                                 int* __restrict__ ccnt,
                                 int* __restrict__ gcurA) {
    extern __shared__ int smem[];
    int* s   = smem;                    // 1024
    int* sfs = smem + 1024;             // nfb+1
    int* sc  = smem + 1024 + nfb + 1;   // 64

    const int tid = threadIdx.x;
    const int ipt = (nfb + 1023) >> 10;   // <= 8 (guarded host-side)
    if (tid < 64) sc[tid] = 0;
    __syncthreads();

    int loc[8];
    int sum = 0;
    const int b0 = tid * ipt;
    for (int k = 0; k < ipt; ++k) {
        const int i = b0 + k;
        int v = 0;
        if (i < nfb) {
            const int c = cnt[i];
            v = (c + 7) & ~7;                 // 64B-aligned bucket regions
            atomicAdd(&sc[i >> 7], c);        // unpadded coarse sums
        }
        loc[k] = sum;
        sum += v;
    }
    s[tid] = sum;
    __syncthreads();
    for (int off = 1; off < 1024; off <<= 1) {
        int t = (tid >= off) ? s[tid - off] : 0;
        __syncthreads();
        s[tid] += t;
        __syncthreads();
    }
    const int excl = s[tid] - sum;
    for (int k = 0; k < ipt; ++k) {
        const int i = b0 + k;
        if (i < nfb) {
            const int f = excl + loc[k];
            fstart[i] = f;
            gfcur[i] = f;
            sfs[i] = f;
        }
    }
    if (tid == 0) {
        const int tot = s[1023];
        fstart[nfb] = tot;
        sfs[nfb] = tot;
    }
    __syncthreads();

    if (tid < ncb) {
        const int st = sfs[min(tid * FPC, nfb)];
        cstart[tid] = st;
        gcurA[tid] = st;
        ccnt[tid] = sc[tid];
    }
    if (tid == ncb) cstart[ncb] = sfs[nfb];
}

// ===========================================================================
// Pass A (both lists, one launch): tile-wise counting sort into coarse
// buckets (8192 rows). lo = col_global(19b) | (row&8191)<<19 ; hi = val.
// ===========================================================================
#define TA 2048
__global__ void passA2_kernel(const int* __restrict__ u_row,
                              const int* __restrict__ u_col,
                              const float* __restrict__ u_val, int e_u,
                              const int* __restrict__ i_row,
                              const int* __restrict__ i_col,
                              const float* __restrict__ i_val, int e_i,
                              int n_u, int tiles_u,
                              int* __restrict__ gcurA,
                              int2* __restrict__ stagA, int ncb) {
    __shared__ int elo[TA], ehi[TA], ebk[TA];
    __shared__ int cnt[64], base[64], gb[64];
    const int tid = threadIdx.x;
    const int bid = blockIdx.x;

    const bool is_u = bid < tiles_u;
    const int* __restrict__ rows = is_u ? u_row : i_row;
    const int* __restrict__ cols = is_u ? u_col : i_col;
    const float* __restrict__ vals = is_u ? u_val : i_val;
    const int n_edges = is_u ? e_u : e_i;
    const int off = is_u ? 0 : n_u;
    const int tstart = (is_u ? bid : bid - tiles_u) * TA;
    const int tn = min(TA, n_edges - tstart);

    if (tid < 64) cnt[tid] = 0;
    __syncthreads();

    int mylo[8], myhi[8], mycb[8], myrk[8];
    #pragma unroll
    for (int j = 0; j < 8; ++j) {
        const int t = tid + j * 256;
        mycb[j] = -1;
        if (t < tn) {
            const int e = tstart + t;
            const int r = off + rows[e];
            const int c = off + cols[e];
            const int cb = r >> 13;
            mylo[j] = c | ((r & 8191) << 19);
            myhi[j] = __float_as_int(vals[e]);
            mycb[j] = cb;
            myrk[j] = atomicAdd(&cnt[cb], 1);
        }
    }
    __syncthreads();
    if (tid == 0) {
        int acc = 0;
        for (int b = 0; b < ncb; ++b) { base[b] = acc; acc += cnt[b]; }
    }
    if (tid < ncb) gb[tid] = (cnt[tid] > 0) ? atomicAdd(&gcurA[tid], cnt[tid]) : 0;
    __syncthreads();
    #pragma unroll
    for (int j = 0; j < 8; ++j) {
        if (mycb[j] >= 0) {
            const int pos = base[mycb[j]] + myrk[j];
            elo[pos] = mylo[j];
            ehi[pos] = myhi[j];
            ebk[pos] = mycb[j];
        }
    }
    __syncthreads();
    #pragma unroll
    for (int j = 0; j < 8; ++j) {
        const int t = tid + j * 256;
        if (t < tn) {
            const int b = ebk[t];
            stagA[gb[b] + (t - base[b])] = make_int2(elo[t], ehi[t]);
        }
    }
}

// ===========================================================================
// Pass B: within each coarse region, counting sort into 128 fine buckets
// (64 rows each). fine-in-coarse = (u32)lo >> 25 (7 bits).
// ===========================================================================
#define TB 2048
#define KB 64
__global__ void passB_kernel(const int2* __restrict__ stagA,
                             const int* __restrict__ cstart,
                             const int* __restrict__ ccnt,
                             int* __restrict__ gfcur,
                             int2* __restrict__ stagB, int nfb) {
    __shared__ int elo[TB], ehi[TB];
    __shared__ int cnt[FPC], base[FPC], gb[FPC];
    const int tid = threadIdx.x;
    const int cb = blockIdx.x / KB;
    const int k  = blockIdx.x % KB;
    const int s = cstart[cb];
    const int n = ccnt[cb];
    const int chunk = (n + KB - 1) / KB;
    const int lo_i = k * chunk;
    const int hi_i = min(n, lo_i + chunk);

    for (int t0 = lo_i; t0 < hi_i; t0 += TB) {
        const int tn = min(TB, hi_i - t0);

        __syncthreads();
        if (tid < FPC) cnt[tid] = 0;
        __syncthreads();

        int mylo[8], myhi[8], myfb[8], myrk[8];
        #pragma unroll
        for (int j = 0; j < 8; ++j) {
            const int t = tid + j * 256;
            myfb[j] = -1;
            if (t < tn) {
                const int2 e = stagA[s + t0 + t];
                const int f = (int)(((u32)e.x) >> 25);
                mylo[j] = e.x;
                myhi[j] = e.y;
                myfb[j] = f;
                myrk[j] = atomicAdd(&cnt[f], 1);
            }
        }
        __syncthreads();
        if (tid == 0) {
            int acc = 0;
            for (int b = 0; b < FPC; ++b) { base[b] = acc; acc += cnt[b]; }
        }
        if (tid < FPC) {
            const int idx = cb * FPC + tid;
            gb[tid] = (idx < nfb && cnt[tid] > 0) ? atomicAdd(&gfcur[idx], cnt[tid]) : 0;
        }
        __syncthreads();
        #pragma unroll
        for (int j = 0; j < 8; ++j) {
            if (myfb[j] >= 0) {
                const int pos = base[myfb[j]] + myrk[j];
                elo[pos] = mylo[j];
                ehi[pos] = myhi[j];
            }
        }
        __syncthreads();
        #pragma unroll
        for (int j = 0; j < 8; ++j) {
            const int t = tid + j * 256;
            if (t < tn) {
                const int b = (int)(((u32)elo[t]) >> 25);
                stagB[gb[b] + (t - base[b])] = make_int2(elo[t], ehi[t]);
            }
        }
    }
}

// ===========================================================================
// Pass C (exact R7 body): one block per 64-row fine bucket. In-LDS counting
// sort by exact row (two 32-row halves), then per-wave REGISTER-accumulated
// row gather, one coalesced 256B store per row.
// ===========================================================================
#define EC 2048
__global__ void passC_kernel(const unsigned short* __restrict__ Ybf,
                             const int2* __restrict__ stagB,
                             const int* __restrict__ fstart,
                             const int* __restrict__ cnt,
                             float* __restrict__ out, int n_rows) {
    __shared__ int2 eds[EC];
    __shared__ int rcnt[64];
    __shared__ int rptr[65];
    const int tid = threadIdx.x;
    const int lane = tid & 63;
    const int wid = tid >> 6;
    const int fb = blockIdx.x;
    const int s = fstart[fb];
    const int n = cnt[fb];
    const int row0 = fb << 6;
    const int rows_here = min(64, n_rows - row0);

    if (n == 0) {  // leaky(0) = 0, but out must still be written
        for (int i = tid; i < rows_here * 16; i += 256)
            ((float4*)(out + (size_t)row0 * 64))[i] = make_float4(0.f, 0.f, 0.f, 0.f);
        return;
    }

    if (tid < 64) rcnt[tid] = 0;
    __syncthreads();

    // rank all bucket edges by exact row (6 bits at lo>>19)
    int mylo[8], myhi[8], myrb[8], myrk[8];
    #pragma unroll
    for (int j = 0; j < 8; ++j) {
        const int t = tid + j * 256;
        myrb[j] = -1;
        if (t < n && t < EC) {
            const int2 e = stagB[s + t];
            const int rb = (e.x >> 19) & 63;
            mylo[j] = e.x;
            myhi[j] = e.y;
            myrb[j] = rb;
            myrk[j] = atomicAdd(&rcnt[rb], 1);
        }
    }
    __syncthreads();
    if (tid == 0) {
        int acc = 0;
        for (int b = 0; b < 64; ++b) { rptr[b] = acc; acc += rcnt[b]; }
        rptr[64] = acc;
    }
    __syncthreads();

    for (int h = 0; h < 2; ++h) {
        const int hbase = rptr[h * 32];
        #pragma unroll
        for (int j = 0; j < 8; ++j) {
            const int rb = myrb[j];
            if (rb >= h * 32 && rb < (h + 1) * 32) {
                const int pos = rptr[rb] + myrk[j] - hbase;
                if (pos < EC) eds[pos] = make_int2(mylo[j], myhi[j]);
            }
        }
        __syncthreads();
        for (int rr = 0; rr < 8; ++rr) {
            const int rl = h * 32 + wid * 8 + rr;
            const int js = rptr[rl] - hbase;
            const int je = rptr[rl + 1] - hbase;
            float a0 = 0.f, a1 = 0.f, a2 = 0.f, a3 = 0.f;
            int j = js;
            for (; j + 4 <= je; j += 4) {
                const int2 e0 = eds[j];
                const int2 e1 = eds[j + 1];
                const int2 e2 = eds[j + 2];
                const int2 e3 = eds[j + 3];
                const float y0 = bf16_to_f32(Ybf[(size_t)(e0.x & 0x7FFFF) * 64 + lane]);
                const float y1 = bf16_to_f32(Ybf[(size_t)(e1.x & 0x7FFFF) * 64 + lane]);
                const float y2 = bf16_to_f32(Ybf[(size_t)(e2.x & 0x7FFFF) * 64 + lane]);
                const float y3 = bf16_to_f32(Ybf[(size_t)(e3.x & 0x7FFFF) * 64 + lane]);
                a0 = fmaf(__int_as_float(e0.y), y0, a0);
                a1 = fmaf(__int_as_float(e1.y), y1, a1);
                a2 = fmaf(__int_as_float(e2.y), y2, a2);
                a3 = fmaf(__int_as_float(e3.y), y3, a3);
            }
            for (; j < je; ++j) {
                const int2 e0 = eds[j];
                a0 = fmaf(__int_as_float(e0.y),
                          bf16_to_f32(Ybf[(size_t)(e0.x & 0x7FFFF) * 64 + lane]), a0);
            }
            const int rgl = row0 + rl;
            if (rgl < n_rows) {
                const float a = (a0 + a1) + (a2 + a3);
                out[(size_t)rgl * 64 + lane] = a > 0.f ? a : NEG_SLOPE * a;
            }
        }
        __syncthreads();
    }
}

// ===========================================================================
extern "C" void kernel_launch(void* const* d_in, const int* in_sizes, int n_in,
                              void* d_out, int out_size, void* d_ws, size_t ws_size,
                              hipStream_t stream) {
    const float* users_emb = (const float*)d_in[0];
    const float* items_emb = (const float*)d_in[1];
    const int*   u_row     = (const int*)d_in[2];
    const int*   u_col     = (const int*)d_in[3];
    const float* u_val     = (const float*)d_in[4];
    const int*   i_row     = (const int*)d_in[5];
    const int*   i_col     = (const int*)d_in[6];
    const float* i_val     = (const float*)d_in[7];
    const float* W_u       = (const float*)d_in[8];
    const float* W_i       = (const float*)d_in[9];

    const int n_u = in_sizes[0] / 64;           // 100000
    const int n_i = in_sizes[1] / 64;           // 200000
    const int e_u = in_sizes[2];                // 1.6M
    const int e_i = in_sizes[5];                // 3.2M
    const int n_rows = n_u + n_i;               // 300000
    const long long E = (long long)e_u + e_i;   // 4.8M

    float* out = (float*)d_out;

    const int BLK = 256;
    const int nfb = (n_rows + 63) >> 6;         // 4688 fine buckets (64 rows)
    const int ncb = (n_rows + 8191) >> 13;      // 37 coarse buckets (8192 rows)
    const long long EPAD = E + (long long)nfb * 8;

    // Workspace layout (word offsets, 4-word aligned sections):
    size_t off = 0;
    #define ALIGN4 off = (off + 3) & ~(size_t)3
    const size_t o_cnt    = off;  off += (size_t)nfb;        ALIGN4;
    const size_t o_fstart = off;  off += (size_t)nfb + 1;    ALIGN4;
    const size_t o_cstart = off;  off += (size_t)ncb + 1;    ALIGN4;
    const size_t o_ccnt   = off;  off += (size_t)ncb;        ALIGN4;
    const size_t o_gcurA  = off;  off += (size_t)ncb;        ALIGN4;
    const size_t o_gfcur  = off;  off += (size_t)nfb;        ALIGN4;
    const size_t o_Y      = off;  off += (size_t)n_rows * 32; ALIGN4;
    const size_t o_stagA  = off;  off += (size_t)EPAD * 2;   ALIGN4;
    const size_t o_stagB  = off;  off += (size_t)EPAD * 2;
    const size_t need_bytes = off * 4;

    if (ws_size >= need_bytes && nfb <= 8192 && ncb <= 63) {
        int*            cnt    = (int*)d_ws + o_cnt;
        int*            fstart = (int*)d_ws + o_fstart;
        int*            cstart = (int*)d_ws + o_cstart;
        int*            ccnt   = (int*)d_ws + o_ccnt;
        int*            gcurA  = (int*)d_ws + o_gcurA;
        int*            gfcur  = (int*)d_ws + o_gfcur;
        unsigned short* Ybf    = (unsigned short*)((int*)d_ws + o_Y);
        int2*           stagA  = (int2*)((int*)d_ws + o_stagA);
        int2*           stagB  = (int2*)((int*)d_ws + o_stagB);

        // 1) pre-transform (independent of binning)
        const int tiles_u_pt = (n_u + PT_ROWS - 1) / PT_ROWS;
        const int tiles_i_pt = (n_i + PT_ROWS - 1) / PT_ROWS;
        pretransform_both_kernel<<<tiles_u_pt + tiles_i_pt, BLK, 0, stream>>>(
            users_emb, items_emb, W_u, W_i, Ybf, n_u, n_i, tiles_u_pt);

        // 2) fine histogram (both lists, one launch; 512 blocks, 18.75KB LDS)
        hipMemsetAsync(cnt, 0, (size_t)nfb * 4, stream);
        const size_t hist_lds = (size_t)nfb * 4;
        hist_fine2_kernel<<<512, BLK, hist_lds, stream>>>(u_row, e_u, i_row, e_i,
                                                          n_u, cnt, nfb);

        // 3) scan + all cursor/coarse init in ONE single-block kernel
        const size_t si_lds = (size_t)(1024 + nfb + 1 + 64) * 4;
        scan_init_kernel<<<1, 1024, si_lds, stream>>>(cnt, nfb, ncb, fstart,
                                                      gfcur, cstart, ccnt, gcurA);

        // 4) pass A: coarse binning (both lists, one launch)
        const int tiles_u_a = (e_u + TA - 1) / TA;
        const int tiles_i_a = (e_i + TA - 1) / TA;
        passA2_kernel<<<tiles_u_a + tiles_i_a, BLK, 0, stream>>>(
            u_row, u_col, u_val, e_u, i_row, i_col, i_val, e_i,
            n_u, tiles_u_a, gcurA, stagA, ncb);

        // 5) pass B: fine binning (128 bins per coarse)
        passB_kernel<<<ncb * KB, BLK, 0, stream>>>(stagA, cstart, ccnt,
                                                   gfcur, stagB, nfb);

        // 6) pass C: in-LDS row sort + register gather + coalesced store
        passC_kernel<<<nfb, BLK, 0, stream>>>(Ybf, stagB, fstart, cnt, out, n_rows);
    } else {
        // Fallback: atomic scatter + shfl transform (round-1 path, fp32)
        float* out_u = out;
        float* out_i = out + (size_t)n_u * 64;
        hipMemsetAsync(d_out, 0, (size_t)out_size * sizeof(float), stream);
        const int WPB = BLK / 64;
        int grid_u = (e_u + WPB - 1) / WPB;
        int grid_i = (e_i + WPB - 1) / WPB;
        const int SCAP = 256 * 8;
        if (grid_u > SCAP) grid_u = SCAP;
        if (grid_i > SCAP) grid_i = SCAP;
        spmm_scatter_kernel<<<grid_u, BLK, 0, stream>>>(users_emb, u_row, u_col, u_val, out_u, e_u);
        spmm_scatter_kernel<<<grid_i, BLK, 0, stream>>>(items_emb, i_row, i_col, i_val, out_i, e_i);
        int grid_t = (n_rows + WPB - 1) / WPB;
        if (grid_t > 2048) grid_t = 2048;
        transform_leaky_kernel<<<grid_t, BLK, 0, stream>>>(out, W_u, W_i, n_u, n_rows);
    }
}

// Round 12
// 317.108 us; speedup vs baseline: 1.2878x; 1.0029x over previous
//
#include <hip/hip_runtime.h>

#define NEG_SLOPE 0.2f

typedef unsigned int u32;

__device__ __forceinline__ unsigned short f32_to_bf16_rne(float f) {
    u32 u = __float_as_uint(f);
    u = (u + 0x7FFFu + ((u >> 16) & 1u)) >> 16;
    return (unsigned short)u;
}
__device__ __forceinline__ float bf16_to_f32(unsigned short b) {
    return __uint_as_float(((u32)b) << 16);
}

// ===========================================================================
// Fallback path (round-1): edge-parallel atomic scatter + shfl transform.
// ===========================================================================
__global__ void spmm_scatter_kernel(const float* __restrict__ emb,
                                    const int* __restrict__ row,
                                    const int* __restrict__ col,
                                    const float* __restrict__ val,
                                    float* __restrict__ acc,
                                    int n_edges) {
    const int lane = threadIdx.x & 63;
    const int wpb = blockDim.x >> 6;
    const int wib = threadIdx.x >> 6;
    const int total_waves = gridDim.x * wpb;
    for (int e = blockIdx.x * wpb + wib; e < n_edges; e += total_waves) {
        const int r = row[e];
        const int c = col[e];
        const float v = val[e];
        atomicAdd(&acc[(size_t)r * 64 + lane], v * emb[(size_t)c * 64 + lane]);
    }
}

__global__ void transform_leaky_kernel(float* __restrict__ io,
                                       const float* __restrict__ W_u,
                                       const float* __restrict__ W_i,
                                       int n_u_rows, int n_total_rows) {
    __shared__ float Ws[2][64 * 64];
    for (int i = threadIdx.x; i < 64 * 64; i += blockDim.x) {
        Ws[0][i] = W_u[i];
        Ws[1][i] = W_i[i];
    }
    __syncthreads();
    const int lane = threadIdx.x & 63;
    const int wpb = blockDim.x >> 6;
    const int wib = threadIdx.x >> 6;
    const int total_waves = gridDim.x * wpb;
    for (int r = blockIdx.x * wpb + wib; r < n_total_rows; r += total_waves) {
        const float* W = (r < n_u_rows) ? Ws[0] : Ws[1];
        const float hv = io[(size_t)r * 64 + lane];
        float acc = 0.0f;
        #pragma unroll
        for (int k = 0; k < 64; ++k) {
            const float hk = __shfl(hv, k, 64);
            acc = fmaf(hk, W[k * 64 + lane], acc);
        }
        io[(size_t)r * 64 + lane] = acc > 0.0f ? acc : NEG_SLOPE * acc;
    }
}

// ===========================================================================
// FUSED hist + pre-transform, occupancy-preserving version:
//   - hist role (blocks 0..HB2-1): 18.75KB dynamic LDS histogram, identical
//     parallelism (512 blocks) to the standalone kernel.
//   - pt role (blocks HB2..): stages ONLY W in the first 16KB of the same
//     dynamic LDS; per-row h vectors are read directly from global (uniform
//     float4 per 16-lane group -> L1 broadcast). No hs tile => no 33.8KB
//     union => both roles keep 8 blocks/CU.
// ===========================================================================
#define PT_ROWS 64
#define HB2 512

__global__ void fused_hist_pt_kernel(const float* __restrict__ uemb,
                                     const float* __restrict__ iemb,
                                     const float* __restrict__ W_u,
                                     const float* __restrict__ W_i,
                                     unsigned short* __restrict__ Ybf,
                                     int n_u, int n_i, int tiles_u,
                                     const int* __restrict__ u_row, int e_u,
                                     const int* __restrict__ i_row, int e_i,
                                     int* __restrict__ counts, int nfb) {
    extern __shared__ int dyn[];

    if (blockIdx.x < HB2) {
        // ---------------- histogram role ----------------
        int* lh = dyn;
        for (int i = threadIdx.x; i < nfb; i += blockDim.x) lh[i] = 0;
        __syncthreads();
        const int tid = blockIdx.x * blockDim.x + threadIdx.x;
        const int stride = HB2 * blockDim.x;

        const int n41 = e_u >> 2;
        for (int g = tid; g < n41; g += stride) {
            const int4 r4 = ((const int4*)u_row)[g];
            atomicAdd(&lh[r4.x >> 6], 1);
            atomicAdd(&lh[r4.y >> 6], 1);
            atomicAdd(&lh[r4.z >> 6], 1);
            atomicAdd(&lh[r4.w >> 6], 1);
        }
        for (int e = (n41 << 2) + tid; e < e_u; e += stride)
            atomicAdd(&lh[u_row[e] >> 6], 1);

        const int n42 = e_i >> 2;
        for (int g = tid; g < n42; g += stride) {
            const int4 r4 = ((const int4*)i_row)[g];
            atomicAdd(&lh[(n_u + r4.x) >> 6], 1);
            atomicAdd(&lh[(n_u + r4.y) >> 6], 1);
            atomicAdd(&lh[(n_u + r4.z) >> 6], 1);
            atomicAdd(&lh[(n_u + r4.w) >> 6], 1);
        }
        for (int e = (n42 << 2) + tid; e < e_i; e += stride)
            atomicAdd(&lh[(n_u + i_row[e]) >> 6], 1);

        __syncthreads();
        for (int i = threadIdx.x; i < nfb; i += blockDim.x) {
            const int c = lh[i];
            if (c) atomicAdd(&counts[i], c);
        }
        return;
    }

    // ---------------- pre-transform role ----------------
    float* Ws = (float*)dyn;  // 16 KB: W[k][j] row-major
    const int tile = blockIdx.x - HB2;
    const bool is_u = tile < tiles_u;
    const float* __restrict__ emb = is_u ? uemb : iemb;
    const float* __restrict__ W = is_u ? W_u : W_i;
    const int lt = is_u ? tile : tile - tiles_u;
    const int nr = is_u ? n_u : n_i;
    const int base = lt * PT_ROWS;
    const int rows_here = min(PT_ROWS, nr - base);
    const size_t ybase = (is_u ? (size_t)base : (size_t)n_u + base) * 64;

    const int lane = threadIdx.x & 63;
    const int wid  = threadIdx.x >> 6;
    const int rsub = lane >> 4;
    const int jg   = lane & 15;

    {
        const float4* src = (const float4*)W;
        float4* dst = (float4*)Ws;
        for (int i = threadIdx.x; i < 64 * 16; i += blockDim.x) dst[i] = src[i];
    }
    __syncthreads();

    #pragma unroll
    for (int quad = 0; quad < 4; ++quad) {
        const int r = (wid + quad * 4) * 4 + rsub;
        if (r < rows_here) {
            const float4* hrow = (const float4*)(emb + (size_t)(base + r) * 64);
            float ax = 0.f, ay = 0.f, az = 0.f, aw = 0.f;
            #pragma unroll
            for (int kq = 0; kq < 16; ++kq) {
                const float4 h = hrow[kq];  // uniform across 16-lane group
                const float4 w0 = *(const float4*)&Ws[(kq * 4 + 0) * 64 + jg * 4];
                const float4 w1 = *(const float4*)&Ws[(kq * 4 + 1) * 64 + jg * 4];
                const float4 w2 = *(const float4*)&Ws[(kq * 4 + 2) * 64 + jg * 4];
                const float4 w3 = *(const float4*)&Ws[(kq * 4 + 3) * 64 + jg * 4];
                ax = fmaf(h.x, w0.x, ax); ay = fmaf(h.x, w0.y, ay);
                az = fmaf(h.x, w0.z, az); aw = fmaf(h.x, w0.w, aw);
                ax = fmaf(h.y, w1.x, ax); ay = fmaf(h.y, w1.y, ay);
                az = fmaf(h.y, w1.z, az); aw = fmaf(h.y, w1.w, aw);
                ax = fmaf(h.z, w2.x, ax); ay = fmaf(h.z, w2.y, ay);
                az = fmaf(h.z, w2.z, az); aw = fmaf(h.z, w2.w, aw);
                ax = fmaf(h.w, w3.x, ax); ay = fmaf(h.w, w3.y, ay);
                az = fmaf(h.w, w3.z, az); aw = fmaf(h.w, w3.w, aw);
            }
            ushort4 o;
            o.x = f32_to_bf16_rne(ax);
            o.y = f32_to_bf16_rne(ay);
            o.z = f32_to_bf16_rne(az);
            o.w = f32_to_bf16_rne(aw);
            *(ushort4*)(Ybf + ybase + (size_t)r * 64 + jg * 4) = o;
        }
    }
}

#define FPC 128  // fine buckets (64 rows) per coarse bucket (8192 rows)

// ===========================================================================
// Single-block scan+init (1024 threads): padded exclusive scan of cnt ->
// fstart/gfcur + coarse starts/counts/cursors.
// LDS (dynamic): s[1024] | sfs[nfb+1] | sc[64]
// ===========================================================================
__global__ void scan_init_kernel(const int* __restrict__ cnt, int nfb, int ncb,
                                 int* __restrict__ fstart,
                                 int* __restrict__ gfcur,
                                 int* __restrict__ cstart,
                                 int* __restrict__ ccnt,
                                 int* __restrict__ gcurA) {
    extern __shared__ int smem[];
    int* s   = smem;                    // 1024
    int* sfs = smem + 1024;             // nfb+1
    int* sc  = smem + 1024 + nfb + 1;   // 64

    const int tid = threadIdx.x;
    const int ipt = (nfb + 1023) >> 10;   // <= 8 (guarded host-side)
    if (tid < 64) sc[tid] = 0;
    __syncthreads();

    int loc[8];
    int sum = 0;
    const int b0 = tid * ipt;
    for (int k = 0; k < ipt; ++k) {
        const int i = b0 + k;
        int v = 0;
        if (i < nfb) {
            const int c = cnt[i];
            v = (c + 7) & ~7;                 // 64B-aligned bucket regions
            atomicAdd(&sc[i >> 7], c);        // unpadded coarse sums
        }
        loc[k] = sum;
        sum += v;
    }
    s[tid] = sum;
    __syncthreads();
    for (int off = 1; off < 1024; off <<= 1) {
        int t = (tid >= off) ? s[tid - off] : 0;
        __syncthreads();
        s[tid] += t;
        __syncthreads();
    }
    const int excl = s[tid] - sum;
    for (int k = 0; k < ipt; ++k) {
        const int i = b0 + k;
        if (i < nfb) {
            const int f = excl + loc[k];
            fstart[i] = f;
            gfcur[i] = f;
            sfs[i] = f;
        }
    }
    if (tid == 0) {
        const int tot = s[1023];
        fstart[nfb] = tot;
        sfs[nfb] = tot;
    }
    __syncthreads();

    if (tid < ncb) {
        const int st = sfs[min(tid * FPC, nfb)];
        cstart[tid] = st;
        gcurA[tid] = st;
        ccnt[tid] = sc[tid];
    }
    if (tid == ncb) cstart[ncb] = sfs[nfb];
}

// ===========================================================================
// Pass A (both lists, one launch): tile-wise counting sort into coarse
// buckets (8192 rows). lo = col_global(19b) | (row&8191)<<19 ; hi = val.
// ===========================================================================
#define TA 2048
__global__ void passA2_kernel(const int* __restrict__ u_row,
                              const int* __restrict__ u_col,
                              const float* __restrict__ u_val, int e_u,
                              const int* __restrict__ i_row,
                              const int* __restrict__ i_col,
                              const float* __restrict__ i_val, int e_i,
                              int n_u, int tiles_u,
                              int* __restrict__ gcurA,
                              int2* __restrict__ stagA, int ncb) {
    __shared__ int elo[TA], ehi[TA], ebk[TA];
    __shared__ int cnt[64], base[64], gb[64];
    const int tid = threadIdx.x;
    const int bid = blockIdx.x;

    const bool is_u = bid < tiles_u;
    const int* __restrict__ rows = is_u ? u_row : i_row;
    const int* __restrict__ cols = is_u ? u_col : i_col;
    const float* __restrict__ vals = is_u ? u_val : i_val;
    const int n_edges = is_u ? e_u : e_i;
    const int off = is_u ? 0 : n_u;
    const int tstart = (is_u ? bid : bid - tiles_u) * TA;
    const int tn = min(TA, n_edges - tstart);

    if (tid < 64) cnt[tid] = 0;
    __syncthreads();

    int mylo[8], myhi[8], mycb[8], myrk[8];
    #pragma unroll
    for (int j = 0; j < 8; ++j) {
        const int t = tid + j * 256;
        mycb[j] = -1;
        if (t < tn) {
            const int e = tstart + t;
            const int r = off + rows[e];
            const int c = off + cols[e];
            const int cb = r >> 13;
            mylo[j] = c | ((r & 8191) << 19);
            myhi[j] = __float_as_int(vals[e]);
            mycb[j] = cb;
            myrk[j] = atomicAdd(&cnt[cb], 1);
        }
    }
    __syncthreads();
    if (tid == 0) {
        int acc = 0;
        for (int b = 0; b < ncb; ++b) { base[b] = acc; acc += cnt[b]; }
    }
    if (tid < ncb) gb[tid] = (cnt[tid] > 0) ? atomicAdd(&gcurA[tid], cnt[tid]) : 0;
    __syncthreads();
    #pragma unroll
    for (int j = 0; j < 8; ++j) {
        if (mycb[j] >= 0) {
            const int pos = base[mycb[j]] + myrk[j];
            elo[pos] = mylo[j];
            ehi[pos] = myhi[j];
            ebk[pos] = mycb[j];
        }
    }
    __syncthreads();
    #pragma unroll
    for (int j = 0; j < 8; ++j) {
        const int t = tid + j * 256;
        if (t < tn) {
            const int b = ebk[t];
            stagA[gb[b] + (t - base[b])] = make_int2(elo[t], ehi[t]);
        }
    }
}

// ===========================================================================
// Pass B: within each coarse region, counting sort into 128 fine buckets
// (64 rows each). fine-in-coarse = (u32)lo >> 25 (7 bits).
// ===========================================================================
#define TB 2048
#define KB 64
__global__ void passB_kernel(const int2* __restrict__ stagA,
                             const int* __restrict__ cstart,
                             const int* __restrict__ ccnt,
                             int* __restrict__ gfcur,
                             int2* __restrict__ stagB, int nfb) {
    __shared__ int elo[TB], ehi[TB];
    __shared__ int cnt[FPC], base[FPC], gb[FPC];
    const int tid = threadIdx.x;
    const int cb = blockIdx.x / KB;
    const int k  = blockIdx.x % KB;
    const int s = cstart[cb];
    const int n = ccnt[cb];
    const int chunk = (n + KB - 1) / KB;
    const int lo_i = k * chunk;
    const int hi_i = min(n, lo_i + chunk);

    for (int t0 = lo_i; t0 < hi_i; t0 += TB) {
        const int tn = min(TB, hi_i - t0);

        __syncthreads();
        if (tid < FPC) cnt[tid] = 0;
        __syncthreads();

        int mylo[8], myhi[8], myfb[8], myrk[8];
        #pragma unroll
        for (int j = 0; j < 8; ++j) {
            const int t = tid + j * 256;
            myfb[j] = -1;
            if (t < tn) {
                const int2 e = stagA[s + t0 + t];
                const int f = (int)(((u32)e.x) >> 25);
                mylo[j] = e.x;
                myhi[j] = e.y;
                myfb[j] = f;
                myrk[j] = atomicAdd(&cnt[f], 1);
            }
        }
        __syncthreads();
        if (tid == 0) {
            int acc = 0;
            for (int b = 0; b < FPC; ++b) { base[b] = acc; acc += cnt[b]; }
        }
        if (tid < FPC) {
            const int idx = cb * FPC + tid;
            gb[tid] = (idx < nfb && cnt[tid] > 0) ? atomicAdd(&gfcur[idx], cnt[tid]) : 0;
        }
        __syncthreads();
        #pragma unroll
        for (int j = 0; j < 8; ++j) {
            if (myfb[j] >= 0) {
                const int pos = base[myfb[j]] + myrk[j];
                elo[pos] = mylo[j];
                ehi[pos] = myhi[j];
            }
        }
        __syncthreads();
        #pragma unroll
        for (int j = 0; j < 8; ++j) {
            const int t = tid + j * 256;
            if (t < tn) {
                const int b = (int)(((u32)elo[t]) >> 25);
                stagB[gb[b] + (t - base[b])] = make_int2(elo[t], ehi[t]);
            }
        }
    }
}

// ===========================================================================
// Pass C (exact R7 body): one block per 64-row fine bucket. In-LDS counting
// sort by exact row (two 32-row halves), then per-wave REGISTER-accumulated
// row gather, one coalesced 256B store per row.
// ===========================================================================
#define EC 2048
__global__ void passC_kernel(const unsigned short* __restrict__ Ybf,
                             const int2* __restrict__ stagB,
                             const int* __restrict__ fstart,
                             const int* __restrict__ cnt,
                             float* __restrict__ out, int n_rows) {
    __shared__ int2 eds[EC];
    __shared__ int rcnt[64];
    __shared__ int rptr[65];
    const int tid = threadIdx.x;
    const int lane = tid & 63;
    const int wid = tid >> 6;
    const int fb = blockIdx.x;
    const int s = fstart[fb];
    const int n = cnt[fb];
    const int row0 = fb << 6;
    const int rows_here = min(64, n_rows - row0);

    if (n == 0) {  // leaky(0) = 0, but out must still be written
        for (int i = tid; i < rows_here * 16; i += 256)
            ((float4*)(out + (size_t)row0 * 64))[i] = make_float4(0.f, 0.f, 0.f, 0.f);
        return;
    }

    if (tid < 64) rcnt[tid] = 0;
    __syncthreads();

    // rank all bucket edges by exact row (6 bits at lo>>19)
    int mylo[8], myhi[8], myrb[8], myrk[8];
    #pragma unroll
    for (int j = 0; j < 8; ++j) {
        const int t = tid + j * 256;
        myrb[j] = -1;
        if (t < n && t < EC) {
            const int2 e = stagB[s + t];
            const int rb = (e.x >> 19) & 63;
            mylo[j] = e.x;
            myhi[j] = e.y;
            myrb[j] = rb;
            myrk[j] = atomicAdd(&rcnt[rb], 1);
        }
    }
    __syncthreads();
    if (tid == 0) {
        int acc = 0;
        for (int b = 0; b < 64; ++b) { rptr[b] = acc; acc += rcnt[b]; }
        rptr[64] = acc;
    }
    __syncthreads();

    for (int h = 0; h < 2; ++h) {
        const int hbase = rptr[h * 32];
        #pragma unroll
        for (int j = 0; j < 8; ++j) {
            const int rb = myrb[j];
            if (rb >= h * 32 && rb < (h + 1) * 32) {
                const int pos = rptr[rb] + myrk[j] - hbase;
                if (pos < EC) eds[pos] = make_int2(mylo[j], myhi[j]);
            }
        }
        __syncthreads();
        for (int rr = 0; rr < 8; ++rr) {
            const int rl = h * 32 + wid * 8 + rr;
            const int js = rptr[rl] - hbase;
            const int je = rptr[rl + 1] - hbase;
            float a0 = 0.f, a1 = 0.f, a2 = 0.f, a3 = 0.f;
            int j = js;
            for (; j + 4 <= je; j += 4) {
                const int2 e0 = eds[j];
                const int2 e1 = eds[j + 1];
                const int2 e2 = eds[j + 2];
                const int2 e3 = eds[j + 3];
                const float y0 = bf16_to_f32(Ybf[(size_t)(e0.x & 0x7FFFF) * 64 + lane]);
                const float y1 = bf16_to_f32(Ybf[(size_t)(e1.x & 0x7FFFF) * 64 + lane]);
                const float y2 = bf16_to_f32(Ybf[(size_t)(e2.x & 0x7FFFF) * 64 + lane]);
                const float y3 = bf16_to_f32(Ybf[(size_t)(e3.x & 0x7FFFF) * 64 + lane]);
                a0 = fmaf(__int_as_float(e0.y), y0, a0);
                a1 = fmaf(__int_as_float(e1.y), y1, a1);
                a2 = fmaf(__int_as_float(e2.y), y2, a2);
                a3 = fmaf(__int_as_float(e3.y), y3, a3);
            }
            for (; j < je; ++j) {
                const int2 e0 = eds[j];
                a0 = fmaf(__int_as_float(e0.y),
                          bf16_to_f32(Ybf[(size_t)(e0.x & 0x7FFFF) * 64 + lane]), a0);
            }
            const int rgl = row0 + rl;
            if (rgl < n_rows) {
                const float a = (a0 + a1) + (a2 + a3);
                out[(size_t)rgl * 64 + lane] = a > 0.f ? a : NEG_SLOPE * a;
            }
        }
        __syncthreads();
    }
}

// ===========================================================================
extern "C" void kernel_launch(void* const* d_in, const int* in_sizes, int n_in,
                              void* d_out, int out_size, void* d_ws, size_t ws_size,
                              hipStream_t stream) {
    const float* users_emb = (const float*)d_in[0];
    const float* items_emb = (const float*)d_in[1];
    const int*   u_row     = (const int*)d_in[2];
    const int*   u_col     = (const int*)d_in[3];
    const float* u_val     = (const float*)d_in[4];
    const int*   i_row     = (const int*)d_in[5];
    const int*   i_col     = (const int*)d_in[6];
    const float* i_val     = (const float*)d_in[7];
    const float* W_u       = (const float*)d_in[8];
    const float* W_i       = (const float*)d_in[9];

    const int n_u = in_sizes[0] / 64;           // 100000
    const int n_i = in_sizes[1] / 64;           // 200000
    const int e_u = in_sizes[2];                // 1.6M
    const int e_i = in_sizes[5];                // 3.2M
    const int n_rows = n_u + n_i;               // 300000
    const long long E = (long long)e_u + e_i;   // 4.8M

    float* out = (float*)d_out;

    const int BLK = 256;
    const int nfb = (n_rows + 63) >> 6;         // 4688 fine buckets (64 rows)
    const int ncb = (n_rows + 8191) >> 13;      // 37 coarse buckets (8192 rows)
    const long long EPAD = E + (long long)nfb * 8;

    // Workspace layout (word offsets, 4-word aligned sections):
    size_t off = 0;
    #define ALIGN4 off = (off + 3) & ~(size_t)3
    const size_t o_cnt    = off;  off += (size_t)nfb;        ALIGN4;
    const size_t o_fstart = off;  off += (size_t)nfb + 1;    ALIGN4;
    const size_t o_cstart = off;  off += (size_t)ncb + 1;    ALIGN4;
    const size_t o_ccnt   = off;  off += (size_t)ncb;        ALIGN4;
    const size_t o_gcurA  = off;  off += (size_t)ncb;        ALIGN4;
    const size_t o_gfcur  = off;  off += (size_t)nfb;        ALIGN4;
    const size_t o_Y      = off;  off += (size_t)n_rows * 32; ALIGN4;
    const size_t o_stagA  = off;  off += (size_t)EPAD * 2;   ALIGN4;
    const size_t o_stagB  = off;  off += (size_t)EPAD * 2;
    const size_t need_bytes = off * 4;

    if (ws_size >= need_bytes && nfb <= 8192 && ncb <= 63) {
        int*            cnt    = (int*)d_ws + o_cnt;
        int*            fstart = (int*)d_ws + o_fstart;
        int*            cstart = (int*)d_ws + o_cstart;
        int*            ccnt   = (int*)d_ws + o_ccnt;
        int*            gcurA  = (int*)d_ws + o_gcurA;
        int*            gfcur  = (int*)d_ws + o_gfcur;
        unsigned short* Ybf    = (unsigned short*)((int*)d_ws + o_Y);
        int2*           stagA  = (int2*)((int*)d_ws + o_stagA);
        int2*           stagB  = (int2*)((int*)d_ws + o_stagB);

        // 1) fused hist + pre-transform (both keep standalone occupancy)
        hipMemsetAsync(cnt, 0, (size_t)nfb * 4, stream);
        const int tiles_u_pt = (n_u + PT_ROWS - 1) / PT_ROWS;
        const int tiles_i_pt = (n_i + PT_ROWS - 1) / PT_ROWS;
        const size_t fh_lds = (size_t)nfb * 4;  // 18.75 KB >= 16 KB for Ws
        fused_hist_pt_kernel<<<HB2 + tiles_u_pt + tiles_i_pt, BLK, fh_lds, stream>>>(
            users_emb, items_emb, W_u, W_i, Ybf, n_u, n_i, tiles_u_pt,
            u_row, e_u, i_row, e_i, cnt, nfb);

        // 2) scan + all cursor/coarse init in ONE single-block kernel
        const size_t si_lds = (size_t)(1024 + nfb + 1 + 64) * 4;
        scan_init_kernel<<<1, 1024, si_lds, stream>>>(cnt, nfb, ncb, fstart,
                                                      gfcur, cstart, ccnt, gcurA);

        // 3) pass A: coarse binning (both lists, one launch)
        const int tiles_u_a = (e_u + TA - 1) / TA;
        const int tiles_i_a = (e_i + TA - 1) / TA;
        passA2_kernel<<<tiles_u_a + tiles_i_a, BLK, 0, stream>>>(
            u_row, u_col, u_val, e_u, i_row, i_col, i_val, e_i,
            n_u, tiles_u_a, gcurA, stagA, ncb);

        // 4) pass B: fine binning (128 bins per coarse)
        passB_kernel<<<ncb * KB, BLK, 0, stream>>>(stagA, cstart, ccnt,
                                                   gfcur, stagB, nfb);

        // 5) pass C: in-LDS row sort + register gather + coalesced store
        passC_kernel<<<nfb, BLK, 0, stream>>>(Ybf, stagB, fstart, cnt, out, n_rows);
    } else {
        // Fallback: atomic scatter + shfl transform (round-1 path, fp32)
        float* out_u = out;
        float* out_i = out + (size_t)n_u * 64;
        hipMemsetAsync(d_out, 0, (size_t)out_size * sizeof(float), stream);
        const int WPB = BLK / 64;
        int grid_u = (e_u + WPB - 1) / WPB;
        int grid_i = (e_i + WPB - 1) / WPB;
        const int SCAP = 256 * 8;
        if (grid_u > SCAP) grid_u = SCAP;
        if (grid_i > SCAP) grid_i = SCAP;
        spmm_scatter_kernel<<<grid_u, BLK, 0, stream>>>(users_emb, u_row, u_col, u_val, out_u, e_u);
        spmm_scatter_kernel<<<grid_i, BLK, 0, stream>>>(items_emb, i_row, i_col, i_val, out_i, e_i);
        int grid_t = (n_rows + WPB - 1) / WPB;
        if (grid_t > 2048) grid_t = 2048;
        transform_leaky_kernel<<<grid_t, BLK, 0, stream>>>(out, W_u, W_i, n_u, n_rows);
    }
}